// Round 7
// baseline (874.448 us; speedup 1.0000x reference)
//
#include <hip/hip_runtime.h>
#include <math.h>

#define IN_FEATS 64
#define N_NODES 100000
#define N_EDGES 1600000
#define BSHIFT 7
#define NPB 128                       // nodes per bucket = 1<<BSHIFT
#define NBUCK ((N_NODES + NPB - 1) / NPB)   // 782
#define PCHUNK 8192
#define PGRID ((N_EDGES + PCHUNK - 1) / PCHUNK)  // 196

// ---------------------------------------------------------------------------
// edge coefficient: rbf(d, mu_k) * smooth_cutoff(d)
// ---------------------------------------------------------------------------
__device__ __forceinline__ float edge_coef(float d, float mu) {
    float t = d - mu;
    float rbf = __expf(-64.0f * t * t);          // gamma = 64/(1-0)
    float x  = (d - 0.8f) * 5.0f;                // /(1.0-0.8)
    float xc = fminf(fmaxf(x, 0.0f), 1.0f);
    float ramp = 0.5f * (__cosf(3.14159265358979323846f * xc) + 1.0f);
    float fc = (d <= 0.8f) ? 1.0f : ((d >= 1.0f) ? 0.0f : ramp);
    return rbf * fc;
}

// ---------------------------------------------------------------------------
// Bucket histogram: per-block LDS histogram, one global atomic per bucket.
// ---------------------------------------------------------------------------
__global__ __launch_bounds__(256) void bcount_kernel(const int* __restrict__ dst,
                                                     int* __restrict__ bcnt) {
    __shared__ int hist[NBUCK];
    int tid = threadIdx.x;
    for (int i = tid; i < NBUCK; i += 256) hist[i] = 0;
    __syncthreads();
    int e0 = blockIdx.x * PCHUNK;
    int e1 = min(e0 + PCHUNK, N_EDGES);
    for (int t = e0 + tid; t < e1; t += 256)
        atomicAdd(&hist[dst[t] >> BSHIFT], 1);
    __syncthreads();
    for (int i = tid; i < NBUCK; i += 256) {
        int hv = hist[i];
        if (hv) atomicAdd(&bcnt[i], hv);
    }
}

// ---------------------------------------------------------------------------
// Exclusive scan over NBUCK buckets (single block), also inits cursor+sentinel.
// ---------------------------------------------------------------------------
__global__ __launch_bounds__(1024) void bscan_kernel(const int* __restrict__ bcnt,
                                                     int* __restrict__ boffs,
                                                     int* __restrict__ bcursor) {
    __shared__ int lds[1024];
    int tid = threadIdx.x;
    int v = (tid < NBUCK) ? bcnt[tid] : 0;
    lds[tid] = v;
    __syncthreads();
    for (int off = 1; off < 1024; off <<= 1) {
        int x = (tid >= off) ? lds[tid - off] : 0;
        __syncthreads();
        lds[tid] += x;
        __syncthreads();
    }
    if (tid < NBUCK) {
        int excl = lds[tid] - v;
        boffs[tid] = excl;
        bcursor[tid] = excl;
    }
    if (tid == 0) boffs[NBUCK] = N_EDGES;
}

// ---------------------------------------------------------------------------
// Partition: block-chunked reservation. Each block histograms its chunk,
// reserves one contiguous run per bucket (1 global atomic), then writes
// records into its runs -> block-local line fills, no write amplification.
// Record: {src | (dst_local << 17), dist_bits}  (src < 2^17, dst_local < 128)
// ---------------------------------------------------------------------------
__global__ __launch_bounds__(256) void partition_kernel(const int* __restrict__ dst,
                                                        const int* __restrict__ src,
                                                        const float* __restrict__ dist,
                                                        int* __restrict__ bcursor,
                                                        int2* __restrict__ edge_rec) {
    __shared__ int hist[NBUCK];
    __shared__ int base_[NBUCK];
    int tid = threadIdx.x;
    for (int i = tid; i < NBUCK; i += 256) hist[i] = 0;
    __syncthreads();

    int e0 = blockIdx.x * PCHUNK;
    int e1 = min(e0 + PCHUNK, N_EDGES);

    for (int t = e0 + tid; t < e1; t += 256)
        atomicAdd(&hist[dst[t] >> BSHIFT], 1);
    __syncthreads();

    for (int i = tid; i < NBUCK; i += 256) {
        int hv = hist[i];
        if (hv) base_[i] = atomicAdd(&bcursor[i], hv);
        hist[i] = 0;      // reuse as local cursor
    }
    __syncthreads();

    for (int t = e0 + tid; t < e1; t += 256) {
        int d  = dst[t];
        int b  = d >> BSHIFT;
        int r  = atomicAdd(&hist[b], 1);
        int2 rec;
        rec.x = src[t] | ((d & (NPB - 1)) << 17);
        rec.y = __float_as_int(dist[t]);
        edge_rec[base_[b] + r] = rec;
    }
}

// ---------------------------------------------------------------------------
// Aggregation: one block per bucket (128 nodes), accumulators in LDS,
// ds_add_f32 atomics absorb within-bucket dst randomness.
// Lane k owns feature k; edges broadcast via shuffles; unroll 8.
// ---------------------------------------------------------------------------
__global__ __launch_bounds__(256) void agg_bucket_kernel(
    const float* __restrict__ h,
    const int* __restrict__ boffs,
    const int2* __restrict__ edge_rec,
    float* __restrict__ out)
{
    __shared__ float accum[NPB * 64];   // 32 KB

    int tid  = threadIdx.x;
    int lane = tid & 63;
    int w    = tid >> 6;
    int b    = blockIdx.x;

    // zero accumulators (float4: 2048 vec slots / 256 threads = 8 iters)
    float4 z = make_float4(0.f, 0.f, 0.f, 0.f);
    for (int i = tid; i < NPB * 16; i += 256)
        reinterpret_cast<float4*>(accum)[i] = z;
    __syncthreads();

    int beg = boffs[b];
    int end = boffs[b + 1];
    float mu = (float)lane * (1.0f / 63.0f);

    for (int base = beg + w * 64; base < end; base += 256) {
        int nj = min(64, end - base);
        int2 rec = (base + lane < end) ? edge_rec[base + lane] : make_int2(0, 0);
        int recx = rec.x, recy = rec.y;

        if (nj == 64) {
            #pragma unroll
            for (int j0 = 0; j0 < 64; j0 += 8) {
                float hv[8], cf[8];
                int   dl[8];
                #pragma unroll
                for (int u = 0; u < 8; ++u) {
                    int rx = __shfl(recx, j0 + u);
                    int ry = __shfl(recy, j0 + u);
                    int s  = rx & 0x1FFFF;
                    dl[u]  = rx >> 17;
                    hv[u]  = h[(size_t)s * 64 + lane];
                    cf[u]  = edge_coef(__int_as_float(ry), mu);
                }
                #pragma unroll
                for (int u = 0; u < 8; ++u)
                    atomicAdd(&accum[dl[u] * 64 + lane], hv[u] * cf[u]);
            }
        } else {
            for (int j = 0; j < nj; ++j) {
                int rx = __shfl(recx, j);
                int ry = __shfl(recy, j);
                int s  = rx & 0x1FFFF;
                int dl = rx >> 17;
                float hv = h[(size_t)s * 64 + lane];
                float cf = edge_coef(__int_as_float(ry), mu);
                atomicAdd(&accum[dl * 64 + lane], hv * cf);
            }
        }
    }
    __syncthreads();

    // write out 128 rows, coalesced
    int node0 = b * NPB;
    for (int r = w; r < NPB; r += 4) {
        int node = node0 + r;
        if (node < N_NODES)
            out[(size_t)node * 64 + lane] = accum[r * 64 + lane];
    }
}

// ---------------------------------------------------------------------------
// MLP in place on d_out: out[n] = softplus(agg[n]@W1+b1)@W2+b2
// ---------------------------------------------------------------------------
__global__ __launch_bounds__(256) void mlp_kernel(
    float* __restrict__ io,
    const float* __restrict__ W1, const float* __restrict__ b1,
    const float* __restrict__ W2, const float* __restrict__ b2)
{
    __shared__ float sW1[64 * 64];
    __shared__ float sW2[64 * 64];
    __shared__ float sRow[16][64];
    __shared__ float sHid[16][64];

    int tid = threadIdx.x;
    for (int i = tid; i < 1024; i += 256) {
        reinterpret_cast<float4*>(sW1)[i] = reinterpret_cast<const float4*>(W1)[i];
        reinterpret_cast<float4*>(sW2)[i] = reinterpret_cast<const float4*>(W2)[i];
    }
    __syncthreads();

    int lane = tid & 63;
    int w    = tid >> 6;
    float bb1 = b1[lane];
    float bb2 = b2[lane];

    for (int base = blockIdx.x * 16; base < N_NODES; base += gridDim.x * 16) {
        int n0 = base + w * 4;
        int r  = w * 4;

        sRow[r + 0][lane] = io[(size_t)(n0 + 0) * 64 + lane];
        sRow[r + 1][lane] = io[(size_t)(n0 + 1) * 64 + lane];
        sRow[r + 2][lane] = io[(size_t)(n0 + 2) * 64 + lane];
        sRow[r + 3][lane] = io[(size_t)(n0 + 3) * 64 + lane];

        float a0 = bb1, a1 = bb1, a2 = bb1, a3 = bb1;
        #pragma unroll
        for (int k = 0; k < 64; ++k) {
            float wv = sW1[k * 64 + lane];
            a0 = fmaf(sRow[r + 0][k], wv, a0);
            a1 = fmaf(sRow[r + 1][k], wv, a1);
            a2 = fmaf(sRow[r + 2][k], wv, a2);
            a3 = fmaf(sRow[r + 3][k], wv, a3);
        }
        sHid[r + 0][lane] = (a0 > 20.0f) ? a0 : log1pf(__expf(a0));
        sHid[r + 1][lane] = (a1 > 20.0f) ? a1 : log1pf(__expf(a1));
        sHid[r + 2][lane] = (a2 > 20.0f) ? a2 : log1pf(__expf(a2));
        sHid[r + 3][lane] = (a3 > 20.0f) ? a3 : log1pf(__expf(a3));

        float c0 = bb2, c1 = bb2, c2 = bb2, c3 = bb2;
        #pragma unroll
        for (int k = 0; k < 64; ++k) {
            float wv = sW2[k * 64 + lane];
            c0 = fmaf(sHid[r + 0][k], wv, c0);
            c1 = fmaf(sHid[r + 1][k], wv, c1);
            c2 = fmaf(sHid[r + 2][k], wv, c2);
            c3 = fmaf(sHid[r + 3][k], wv, c3);
        }
        io[(size_t)(n0 + 0) * 64 + lane] = c0;
        io[(size_t)(n0 + 1) * 64 + lane] = c1;
        io[(size_t)(n0 + 2) * 64 + lane] = c2;
        io[(size_t)(n0 + 3) * 64 + lane] = c3;
    }
}

// ---------------------------------------------------------------------------
// Fallback (ws too small): atomic scatter-add path.
// ---------------------------------------------------------------------------
__global__ __launch_bounds__(256) void schnet_edge_kernel(
    const float* __restrict__ h,
    const float* __restrict__ dist,
    const int* __restrict__ src_idx,
    const int* __restrict__ dst_idx,
    float* __restrict__ agg)
{
    long long idx = (long long)blockIdx.x * 256 + threadIdx.x;
    int e = (int)(idx >> 6);
    if (e >= N_EDGES) return;
    int k = (int)(idx & 63);
    float d = dist[e];
    float c = edge_coef(d, (float)k * (1.0f / 63.0f));
    int s  = src_idx[e];
    int dn = dst_idx[e];
    atomicAdd(&agg[(long long)dn * 64 + k], h[(long long)s * 64 + k] * c);
}

extern "C" void kernel_launch(void* const* d_in, const int* in_sizes, int n_in,
                              void* d_out, int out_size, void* d_ws, size_t ws_size,
                              hipStream_t stream) {
    const float* h    = (const float*)d_in[0];
    const float* dist = (const float*)d_in[1];
    const float* W1   = (const float*)d_in[2];
    const float* b1   = (const float*)d_in[3];
    const float* W2   = (const float*)d_in[4];
    const float* b2   = (const float*)d_in[5];
    const int* src    = (const int*)d_in[6];
    const int* dst    = (const int*)d_in[7];
    float* out        = (float*)d_out;

    // ws layout: edge_rec[2*E ints] | bcnt[NBUCK] | boffs[NBUCK+1] | bcursor[NBUCK]
    size_t needed = ((size_t)2 * N_EDGES + 3 * NBUCK + 1) * sizeof(int);

    if (ws_size >= needed) {
        int2* edge_rec = (int2*)d_ws;
        int* bcnt      = (int*)d_ws + (size_t)2 * N_EDGES;
        int* boffs     = bcnt + NBUCK;          // NBUCK+1
        int* bcursor   = boffs + NBUCK + 1;

        hipMemsetAsync(bcnt, 0, NBUCK * sizeof(int), stream);
        bcount_kernel<<<PGRID, 256, 0, stream>>>(dst, bcnt);
        bscan_kernel<<<1, 1024, 0, stream>>>(bcnt, boffs, bcursor);
        partition_kernel<<<PGRID, 256, 0, stream>>>(dst, src, dist, bcursor, edge_rec);
        agg_bucket_kernel<<<NBUCK, 256, 0, stream>>>(h, boffs, edge_rec, out);
    } else {
        hipMemsetAsync(out, 0, (size_t)N_NODES * IN_FEATS * sizeof(float), stream);
        long long total = (long long)N_EDGES * 64;
        schnet_edge_kernel<<<(int)((total + 255) / 256), 256, 0, stream>>>(
            h, dist, src, dst, out);
    }

    mlp_kernel<<<1024, 256, 0, stream>>>(out, W1, b1, W2, b2);
}

// Round 8
// 238.392 us; speedup vs baseline: 3.6681x; 3.6681x over previous
//
#include <hip/hip_runtime.h>
#include <math.h>

#define IN_FEATS 64
#define N_NODES 100000
#define N_EDGES 1600000
#define BSHIFT 7
#define NPB 128                              // nodes per bucket
#define NBUCK ((N_NODES + NPB - 1) / NPB)    // 782
#define PCHUNK 8192
#define PGRID ((N_EDGES + PCHUNK - 1) / PCHUNK)  // 196

// ---------------------------------------------------------------------------
// edge coefficient: rbf(d, mu_k) * smooth_cutoff(d)
// ---------------------------------------------------------------------------
__device__ __forceinline__ float edge_coef(float d, float mu) {
    float t = d - mu;
    float rbf = __expf(-64.0f * t * t);          // gamma = 64/(1-0)
    float x  = (d - 0.8f) * 5.0f;                // /(1.0-0.8)
    float xc = fminf(fmaxf(x, 0.0f), 1.0f);
    float ramp = 0.5f * (__cosf(3.14159265358979323846f * xc) + 1.0f);
    float fc = (d <= 0.8f) ? 1.0f : ((d >= 1.0f) ? 0.0f : ramp);
    return rbf * fc;
}

// ---------------------------------------------------------------------------
// Bucket histogram: per-block LDS histogram, one global atomic per bucket.
// ---------------------------------------------------------------------------
__global__ __launch_bounds__(256) void bcount_kernel(const int* __restrict__ dst,
                                                     int* __restrict__ bcnt) {
    __shared__ int hist[NBUCK];
    int tid = threadIdx.x;
    for (int i = tid; i < NBUCK; i += 256) hist[i] = 0;
    __syncthreads();
    int e0 = blockIdx.x * PCHUNK;
    int e1 = min(e0 + PCHUNK, N_EDGES);
    for (int t = e0 + tid; t < e1; t += 256)
        atomicAdd(&hist[dst[t] >> BSHIFT], 1);
    __syncthreads();
    for (int i = tid; i < NBUCK; i += 256) {
        int hv = hist[i];
        if (hv) atomicAdd(&bcnt[i], hv);
    }
}

// ---------------------------------------------------------------------------
// Exclusive scan over buckets (single block); inits cursor; offs sentinel.
// ---------------------------------------------------------------------------
__global__ __launch_bounds__(1024) void bscan_kernel(const int* __restrict__ bcnt,
                                                     int* __restrict__ boffs,
                                                     int* __restrict__ bcursor,
                                                     int* __restrict__ offs) {
    __shared__ int lds[1024];
    int tid = threadIdx.x;
    int v = (tid < NBUCK) ? bcnt[tid] : 0;
    lds[tid] = v;
    __syncthreads();
    for (int off = 1; off < 1024; off <<= 1) {
        int x = (tid >= off) ? lds[tid - off] : 0;
        __syncthreads();
        lds[tid] += x;
        __syncthreads();
    }
    if (tid < NBUCK) {
        int excl = lds[tid] - v;
        boffs[tid] = excl;
        bcursor[tid] = excl;
    }
    if (tid == 0) {
        boffs[NBUCK] = N_EDGES;
        offs[N_NODES] = N_EDGES;
    }
}

// ---------------------------------------------------------------------------
// Partition into bucket-grouped records (in d_out scratch region).
// Block-chunked reservation: contiguous run per (block,bucket) -> no write amp.
// Record: {src | (dst_local << 17), dist_bits}
// ---------------------------------------------------------------------------
__global__ __launch_bounds__(256) void partition_kernel(const int* __restrict__ dst,
                                                        const int* __restrict__ src,
                                                        const float* __restrict__ dist,
                                                        int* __restrict__ bcursor,
                                                        int2* __restrict__ brec) {
    __shared__ int hist[NBUCK];
    __shared__ int base_[NBUCK];
    int tid = threadIdx.x;
    for (int i = tid; i < NBUCK; i += 256) hist[i] = 0;
    __syncthreads();

    int e0 = blockIdx.x * PCHUNK;
    int e1 = min(e0 + PCHUNK, N_EDGES);

    for (int t = e0 + tid; t < e1; t += 256)
        atomicAdd(&hist[dst[t] >> BSHIFT], 1);
    __syncthreads();

    for (int i = tid; i < NBUCK; i += 256) {
        int hv = hist[i];
        if (hv) base_[i] = atomicAdd(&bcursor[i], hv);
        hist[i] = 0;      // reuse as local cursor
    }
    __syncthreads();

    for (int t = e0 + tid; t < e1; t += 256) {
        int d  = dst[t];
        int b  = d >> BSHIFT;
        int r  = atomicAdd(&hist[b], 1);
        int2 rec;
        rec.x = src[t] | ((d & (NPB - 1)) << 17);
        rec.y = __float_as_int(dist[t]);
        brec[base_[b] + r] = rec;
    }
}

// ---------------------------------------------------------------------------
// Node-sort: one block per bucket. LDS count -> scan -> scatter into per-node
// order (rec_sorted in ws), and emit per-node CSR offs. All reads/writes stay
// in this bucket's contiguous ~16KB range -> no write amplification.
// ---------------------------------------------------------------------------
__global__ __launch_bounds__(256) void node_sort_kernel(const int2* __restrict__ brec,
                                                        const int* __restrict__ boffs,
                                                        int2* __restrict__ rec_sorted,
                                                        int* __restrict__ offs) {
    __shared__ int cntL[NPB];
    __shared__ int scanL[NPB];
    __shared__ int curL[NPB];

    int b   = blockIdx.x;
    int tid = threadIdx.x;
    int beg = boffs[b];
    int end = boffs[b + 1];
    int node0 = b << BSHIFT;

    for (int i = tid; i < NPB; i += 256) cntL[i] = 0;
    __syncthreads();

    for (int t = beg + tid; t < end; t += 256)
        atomicAdd(&cntL[(brec[t].x >> 17) & (NPB - 1)], 1);
    __syncthreads();

    if (tid < NPB) scanL[tid] = cntL[tid];
    __syncthreads();
    for (int off = 1; off < NPB; off <<= 1) {
        int x = 0;
        if (tid < NPB && tid >= off) x = scanL[tid - off];
        __syncthreads();
        if (tid < NPB) scanL[tid] += x;
        __syncthreads();
    }
    if (tid < NPB) {
        int excl = scanL[tid] - cntL[tid];
        curL[tid] = excl;
        int node = node0 + tid;
        if (node < N_NODES) offs[node] = beg + excl;
    }
    __syncthreads();

    for (int t = beg + tid; t < end; t += 256) {
        int2 r = brec[t];
        int dl = (r.x >> 17) & (NPB - 1);
        int p  = atomicAdd(&curL[dl], 1);
        rec_sorted[beg + p] = r;
    }
}

// ---------------------------------------------------------------------------
// Aggregation: one wave per node, lane k owns feature k.
// Padded unroll-8: 8 gathers in flight, uniform control flow.
// ---------------------------------------------------------------------------
__global__ __launch_bounds__(256) void agg_kernel(
    const float* __restrict__ h,
    const int* __restrict__ offs,
    const int2* __restrict__ rec_sorted,
    float* __restrict__ out)
{
    int w    = threadIdx.x >> 6;
    int lane = threadIdx.x & 63;
    int node = blockIdx.x * 4 + w;
    if (node >= N_NODES) return;

    int beg = offs[node];
    int end = offs[node + 1];
    int m   = end - beg;
    float mu = (float)lane * (1.0f / 63.0f);
    float acc = 0.0f;

    const int2* ed = rec_sorted + beg;
    for (int i = 0; i < m; i += 8) {
        float hv[8], cf[8];
        #pragma unroll
        for (int u = 0; u < 8; ++u) {
            int idx = i + u;
            int cl  = (idx < m) ? idx : (m - 1);
            int2 r  = ed[cl];
            int s   = r.x & 0x1FFFF;
            hv[u]   = h[(size_t)s * 64 + lane];
            float c = edge_coef(__int_as_float(r.y), mu);
            cf[u]   = (idx < m) ? c : 0.0f;
        }
        #pragma unroll
        for (int u = 0; u < 8; ++u)
            acc = fmaf(hv[u], cf[u], acc);
    }
    out[(size_t)node * 64 + lane] = acc;
}

// ---------------------------------------------------------------------------
// MLP in place on d_out: out[n] = softplus(agg[n]@W1+b1)@W2+b2
// ---------------------------------------------------------------------------
__global__ __launch_bounds__(256) void mlp_kernel(
    float* __restrict__ io,
    const float* __restrict__ W1, const float* __restrict__ b1,
    const float* __restrict__ W2, const float* __restrict__ b2)
{
    __shared__ float sW1[64 * 64];
    __shared__ float sW2[64 * 64];
    __shared__ float sRow[16][64];
    __shared__ float sHid[16][64];

    int tid = threadIdx.x;
    for (int i = tid; i < 1024; i += 256) {
        reinterpret_cast<float4*>(sW1)[i] = reinterpret_cast<const float4*>(W1)[i];
        reinterpret_cast<float4*>(sW2)[i] = reinterpret_cast<const float4*>(W2)[i];
    }
    __syncthreads();

    int lane = tid & 63;
    int w    = tid >> 6;
    float bb1 = b1[lane];
    float bb2 = b2[lane];

    for (int base = blockIdx.x * 16; base < N_NODES; base += gridDim.x * 16) {
        int n0 = base + w * 4;
        int r  = w * 4;

        sRow[r + 0][lane] = io[(size_t)(n0 + 0) * 64 + lane];
        sRow[r + 1][lane] = io[(size_t)(n0 + 1) * 64 + lane];
        sRow[r + 2][lane] = io[(size_t)(n0 + 2) * 64 + lane];
        sRow[r + 3][lane] = io[(size_t)(n0 + 3) * 64 + lane];

        float a0 = bb1, a1 = bb1, a2 = bb1, a3 = bb1;
        #pragma unroll
        for (int k = 0; k < 64; ++k) {
            float wv = sW1[k * 64 + lane];
            a0 = fmaf(sRow[r + 0][k], wv, a0);
            a1 = fmaf(sRow[r + 1][k], wv, a1);
            a2 = fmaf(sRow[r + 2][k], wv, a2);
            a3 = fmaf(sRow[r + 3][k], wv, a3);
        }
        sHid[r + 0][lane] = (a0 > 20.0f) ? a0 : log1pf(__expf(a0));
        sHid[r + 1][lane] = (a1 > 20.0f) ? a1 : log1pf(__expf(a1));
        sHid[r + 2][lane] = (a2 > 20.0f) ? a2 : log1pf(__expf(a2));
        sHid[r + 3][lane] = (a3 > 20.0f) ? a3 : log1pf(__expf(a3));

        float c0 = bb2, c1 = bb2, c2 = bb2, c3 = bb2;
        #pragma unroll
        for (int k = 0; k < 64; ++k) {
            float wv = sW2[k * 64 + lane];
            c0 = fmaf(sHid[r + 0][k], wv, c0);
            c1 = fmaf(sHid[r + 1][k], wv, c1);
            c2 = fmaf(sHid[r + 2][k], wv, c2);
            c3 = fmaf(sHid[r + 3][k], wv, c3);
        }
        io[(size_t)(n0 + 0) * 64 + lane] = c0;
        io[(size_t)(n0 + 1) * 64 + lane] = c1;
        io[(size_t)(n0 + 2) * 64 + lane] = c2;
        io[(size_t)(n0 + 3) * 64 + lane] = c3;
    }
}

// ---------------------------------------------------------------------------
// Fallback (ws too small): atomic scatter-add path.
// ---------------------------------------------------------------------------
__global__ __launch_bounds__(256) void schnet_edge_kernel(
    const float* __restrict__ h,
    const float* __restrict__ dist,
    const int* __restrict__ src_idx,
    const int* __restrict__ dst_idx,
    float* __restrict__ agg)
{
    long long idx = (long long)blockIdx.x * 256 + threadIdx.x;
    int e = (int)(idx >> 6);
    if (e >= N_EDGES) return;
    int k = (int)(idx & 63);
    float d = dist[e];
    float c = edge_coef(d, (float)k * (1.0f / 63.0f));
    int s  = src_idx[e];
    int dn = dst_idx[e];
    atomicAdd(&agg[(long long)dn * 64 + k], h[(long long)s * 64 + k] * c);
}

extern "C" void kernel_launch(void* const* d_in, const int* in_sizes, int n_in,
                              void* d_out, int out_size, void* d_ws, size_t ws_size,
                              hipStream_t stream) {
    const float* h    = (const float*)d_in[0];
    const float* dist = (const float*)d_in[1];
    const float* W1   = (const float*)d_in[2];
    const float* b1   = (const float*)d_in[3];
    const float* W2   = (const float*)d_in[4];
    const float* b2   = (const float*)d_in[5];
    const int* src    = (const int*)d_in[6];
    const int* dst    = (const int*)d_in[7];
    float* out        = (float*)d_out;

    // ws layout (ints): rec_sorted[2E] | bcnt[NBUCK] | boffs[NBUCK+1] |
    //                   bcursor[NBUCK] | offs[N+1]
    size_t needed = ((size_t)2 * N_EDGES + 3 * NBUCK + 1 + N_NODES + 1) * sizeof(int);

    if (ws_size >= needed) {
        int2* rec_sorted = (int2*)d_ws;
        int* bcnt        = (int*)d_ws + (size_t)2 * N_EDGES;
        int* boffs       = bcnt + NBUCK;           // NBUCK+1
        int* bcursor     = boffs + NBUCK + 1;
        int* offs        = bcursor + NBUCK;        // N+1

        // bucket-ordered records staged in d_out (overwritten by agg later)
        int2* brec = (int2*)d_out;

        hipMemsetAsync(bcnt, 0, NBUCK * sizeof(int), stream);
        bcount_kernel<<<PGRID, 256, 0, stream>>>(dst, bcnt);
        bscan_kernel<<<1, 1024, 0, stream>>>(bcnt, boffs, bcursor, offs);
        partition_kernel<<<PGRID, 256, 0, stream>>>(dst, src, dist, bcursor, brec);
        node_sort_kernel<<<NBUCK, 256, 0, stream>>>(brec, boffs, rec_sorted, offs);
        agg_kernel<<<(N_NODES + 3) / 4, 256, 0, stream>>>(h, offs, rec_sorted, out);
    } else {
        hipMemsetAsync(out, 0, (size_t)N_NODES * IN_FEATS * sizeof(float), stream);
        long long total = (long long)N_EDGES * 64;
        schnet_edge_kernel<<<(int)((total + 255) / 256), 256, 0, stream>>>(
            h, dist, src, dst, out);
    }

    mlp_kernel<<<1024, 256, 0, stream>>>(out, W1, b1, W2, b2);
}

// Round 9
// 218.064 us; speedup vs baseline: 4.0100x; 1.0932x over previous
//
#include <hip/hip_runtime.h>
#include <math.h>

#define IN_FEATS 64
#define N_NODES 100000
#define N_EDGES 1600000
#define BSHIFT 7
#define NPB 128                              // nodes per bucket
#define NBUCK ((N_NODES + NPB - 1) / NPB)    // 782
#define PCHUNK 8192
#define PGRID ((N_EDGES + PCHUNK - 1) / PCHUNK)  // 196

// ---------------------------------------------------------------------------
// edge coefficient: rbf(d, mu_k) * smooth_cutoff(d)
// ---------------------------------------------------------------------------
__device__ __forceinline__ float edge_coef(float d, float mu) {
    float t = d - mu;
    float rbf = __expf(-64.0f * t * t);          // gamma = 64/(1-0)
    float x  = (d - 0.8f) * 5.0f;                // /(1.0-0.8)
    float xc = fminf(fmaxf(x, 0.0f), 1.0f);
    float ramp = 0.5f * (__cosf(3.14159265358979323846f * xc) + 1.0f);
    float fc = (d <= 0.8f) ? 1.0f : ((d >= 1.0f) ? 0.0f : ramp);
    return rbf * fc;
}

__device__ __forceinline__ float rl(float v, int l) {
    return __int_as_float(__builtin_amdgcn_readlane(__float_as_int(v), l));
}

// ---------------------------------------------------------------------------
// Bucket histogram: per-block LDS histogram, one global atomic per bucket.
// ---------------------------------------------------------------------------
__global__ __launch_bounds__(256) void bcount_kernel(const int* __restrict__ dst,
                                                     int* __restrict__ bcnt) {
    __shared__ int hist[NBUCK];
    int tid = threadIdx.x;
    for (int i = tid; i < NBUCK; i += 256) hist[i] = 0;
    __syncthreads();
    int e0 = blockIdx.x * PCHUNK;
    int e1 = min(e0 + PCHUNK, N_EDGES);
    for (int t = e0 + tid; t < e1; t += 256)
        atomicAdd(&hist[dst[t] >> BSHIFT], 1);
    __syncthreads();
    for (int i = tid; i < NBUCK; i += 256) {
        int hv = hist[i];
        if (hv) atomicAdd(&bcnt[i], hv);
    }
}

// ---------------------------------------------------------------------------
// Exclusive scan over buckets (single block); inits cursor; offs sentinel.
// ---------------------------------------------------------------------------
__global__ __launch_bounds__(1024) void bscan_kernel(const int* __restrict__ bcnt,
                                                     int* __restrict__ boffs,
                                                     int* __restrict__ bcursor,
                                                     int* __restrict__ offs) {
    __shared__ int lds[1024];
    int tid = threadIdx.x;
    int v = (tid < NBUCK) ? bcnt[tid] : 0;
    lds[tid] = v;
    __syncthreads();
    for (int off = 1; off < 1024; off <<= 1) {
        int x = (tid >= off) ? lds[tid - off] : 0;
        __syncthreads();
        lds[tid] += x;
        __syncthreads();
    }
    if (tid < NBUCK) {
        int excl = lds[tid] - v;
        boffs[tid] = excl;
        bcursor[tid] = excl;
    }
    if (tid == 0) {
        boffs[NBUCK] = N_EDGES;
        offs[N_NODES] = N_EDGES;
    }
}

// ---------------------------------------------------------------------------
// Partition into bucket-grouped records (in d_out scratch region).
// Block-chunked reservation: contiguous run per (block,bucket) -> no write amp.
// Record: {src | (dst_local << 17), dist_bits}
// ---------------------------------------------------------------------------
__global__ __launch_bounds__(256) void partition_kernel(const int* __restrict__ dst,
                                                        const int* __restrict__ src,
                                                        const float* __restrict__ dist,
                                                        int* __restrict__ bcursor,
                                                        int2* __restrict__ brec) {
    __shared__ int hist[NBUCK];
    __shared__ int base_[NBUCK];
    int tid = threadIdx.x;
    for (int i = tid; i < NBUCK; i += 256) hist[i] = 0;
    __syncthreads();

    int e0 = blockIdx.x * PCHUNK;
    int e1 = min(e0 + PCHUNK, N_EDGES);

    for (int t = e0 + tid; t < e1; t += 256)
        atomicAdd(&hist[dst[t] >> BSHIFT], 1);
    __syncthreads();

    for (int i = tid; i < NBUCK; i += 256) {
        int hv = hist[i];
        if (hv) base_[i] = atomicAdd(&bcursor[i], hv);
        hist[i] = 0;      // reuse as local cursor
    }
    __syncthreads();

    for (int t = e0 + tid; t < e1; t += 256) {
        int d  = dst[t];
        int b  = d >> BSHIFT;
        int r  = atomicAdd(&hist[b], 1);
        int2 rec;
        rec.x = src[t] | ((d & (NPB - 1)) << 17);
        rec.y = __float_as_int(dist[t]);
        brec[base_[b] + r] = rec;
    }
}

// ---------------------------------------------------------------------------
// Node-sort: one block per bucket. LDS count -> scan -> scatter into per-node
// order (rec_sorted in ws), and emit per-node CSR offs.
// ---------------------------------------------------------------------------
__global__ __launch_bounds__(256) void node_sort_kernel(const int2* __restrict__ brec,
                                                        const int* __restrict__ boffs,
                                                        int2* __restrict__ rec_sorted,
                                                        int* __restrict__ offs) {
    __shared__ int cntL[NPB];
    __shared__ int scanL[NPB];
    __shared__ int curL[NPB];

    int b   = blockIdx.x;
    int tid = threadIdx.x;
    int beg = boffs[b];
    int end = boffs[b + 1];
    int node0 = b << BSHIFT;

    for (int i = tid; i < NPB; i += 256) cntL[i] = 0;
    __syncthreads();

    for (int t = beg + tid; t < end; t += 256)
        atomicAdd(&cntL[(brec[t].x >> 17) & (NPB - 1)], 1);
    __syncthreads();

    if (tid < NPB) scanL[tid] = cntL[tid];
    __syncthreads();
    for (int off = 1; off < NPB; off <<= 1) {
        int x = 0;
        if (tid < NPB && tid >= off) x = scanL[tid - off];
        __syncthreads();
        if (tid < NPB) scanL[tid] += x;
        __syncthreads();
    }
    if (tid < NPB) {
        int excl = scanL[tid] - cntL[tid];
        curL[tid] = excl;
        int node = node0 + tid;
        if (node < N_NODES) offs[node] = beg + excl;
    }
    __syncthreads();

    for (int t = beg + tid; t < end; t += 256) {
        int2 r = brec[t];
        int dl = (r.x >> 17) & (NPB - 1);
        int p  = atomicAdd(&curL[dl], 1);
        rec_sorted[beg + p] = r;
    }
}

// ---------------------------------------------------------------------------
// Aggregation: one wave per node, lane k owns feature k.
// Padded unroll-8: 8 gathers in flight, uniform control flow.
// ---------------------------------------------------------------------------
__global__ __launch_bounds__(256) void agg_kernel(
    const float* __restrict__ h,
    const int* __restrict__ offs,
    const int2* __restrict__ rec_sorted,
    float* __restrict__ out)
{
    int w    = threadIdx.x >> 6;
    int lane = threadIdx.x & 63;
    int node = blockIdx.x * 4 + w;
    if (node >= N_NODES) return;

    int beg = offs[node];
    int end = offs[node + 1];
    int m   = end - beg;
    float mu = (float)lane * (1.0f / 63.0f);
    float acc = 0.0f;

    const int2* ed = rec_sorted + beg;
    for (int i = 0; i < m; i += 8) {
        float hv[8], cf[8];
        #pragma unroll
        for (int u = 0; u < 8; ++u) {
            int idx = i + u;
            int cl  = (idx < m) ? idx : (m - 1);
            int2 r  = ed[cl];
            int s   = r.x & 0x1FFFF;
            hv[u]   = h[(size_t)s * 64 + lane];
            float c = edge_coef(__int_as_float(r.y), mu);
            cf[u]   = (idx < m) ? c : 0.0f;
        }
        #pragma unroll
        for (int u = 0; u < 8; ++u)
            acc = fmaf(hv[u], cf[u], acc);
    }
    out[(size_t)node * 64 + lane] = acc;
}

// ---------------------------------------------------------------------------
// MLP in place on d_out: out[n] = softplus(agg[n]@W1+b1)@W2+b2
// Register-resident W columns (128 VGPR); row broadcast via v_readlane —
// ZERO LDS in the inner loop. 2 nodes per wave in flight, 4 acc chains each.
// ---------------------------------------------------------------------------
__global__ __launch_bounds__(256) void mlp_kernel(
    float* __restrict__ io,
    const float* __restrict__ W1, const float* __restrict__ b1,
    const float* __restrict__ W2, const float* __restrict__ b2)
{
    int tid  = threadIdx.x;
    int lane = tid & 63;
    int w    = tid >> 6;

    // W columns for this lane's output feature, kept in VGPRs.
    float w1r[64], w2r[64];
    #pragma unroll
    for (int k = 0; k < 64; ++k) {
        w1r[k] = W1[k * 64 + lane];
        w2r[k] = W2[k * 64 + lane];
    }
    float bb1 = b1[lane];
    float bb2 = b2[lane];

    int wid = blockIdx.x * 4 + w;
    int nw  = gridDim.x * 4;

    for (int n = wid * 2; n < N_NODES; n += nw * 2) {
        float rA = io[(size_t)n * 64 + lane];
        float rB = io[(size_t)(n + 1) * 64 + lane];

        float a0 = bb1, a1 = 0.f, a2 = 0.f, a3 = 0.f;
        float c0 = bb1, c1 = 0.f, c2 = 0.f, c3 = 0.f;
        #pragma unroll
        for (int k = 0; k < 64; k += 4) {
            a0 = fmaf(rl(rA, k + 0), w1r[k + 0], a0);
            a1 = fmaf(rl(rA, k + 1), w1r[k + 1], a1);
            a2 = fmaf(rl(rA, k + 2), w1r[k + 2], a2);
            a3 = fmaf(rl(rA, k + 3), w1r[k + 3], a3);
            c0 = fmaf(rl(rB, k + 0), w1r[k + 0], c0);
            c1 = fmaf(rl(rB, k + 1), w1r[k + 1], c1);
            c2 = fmaf(rl(rB, k + 2), w1r[k + 2], c2);
            c3 = fmaf(rl(rB, k + 3), w1r[k + 3], c3);
        }
        float hA = (a0 + a1) + (a2 + a3);
        float hB = (c0 + c1) + (c2 + c3);
        hA = (hA > 20.0f) ? hA : log1pf(__expf(hA));
        hB = (hB > 20.0f) ? hB : log1pf(__expf(hB));

        float o0 = bb2, o1 = 0.f, o2 = 0.f, o3 = 0.f;
        float p0 = bb2, p1 = 0.f, p2 = 0.f, p3 = 0.f;
        #pragma unroll
        for (int k = 0; k < 64; k += 4) {
            o0 = fmaf(rl(hA, k + 0), w2r[k + 0], o0);
            o1 = fmaf(rl(hA, k + 1), w2r[k + 1], o1);
            o2 = fmaf(rl(hA, k + 2), w2r[k + 2], o2);
            o3 = fmaf(rl(hA, k + 3), w2r[k + 3], o3);
            p0 = fmaf(rl(hB, k + 0), w2r[k + 0], p0);
            p1 = fmaf(rl(hB, k + 1), w2r[k + 1], p1);
            p2 = fmaf(rl(hB, k + 2), w2r[k + 2], p2);
            p3 = fmaf(rl(hB, k + 3), w2r[k + 3], p3);
        }
        io[(size_t)n * 64 + lane]       = (o0 + o1) + (o2 + o3);
        io[(size_t)(n + 1) * 64 + lane] = (p0 + p1) + (p2 + p3);
    }
}

// ---------------------------------------------------------------------------
// Fallback (ws too small): atomic scatter-add path.
// ---------------------------------------------------------------------------
__global__ __launch_bounds__(256) void schnet_edge_kernel(
    const float* __restrict__ h,
    const float* __restrict__ dist,
    const int* __restrict__ src_idx,
    const int* __restrict__ dst_idx,
    float* __restrict__ agg)
{
    long long idx = (long long)blockIdx.x * 256 + threadIdx.x;
    int e = (int)(idx >> 6);
    if (e >= N_EDGES) return;
    int k = (int)(idx & 63);
    float d = dist[e];
    float c = edge_coef(d, (float)k * (1.0f / 63.0f));
    int s  = src_idx[e];
    int dn = dst_idx[e];
    atomicAdd(&agg[(long long)dn * 64 + k], h[(long long)s * 64 + k] * c);
}

extern "C" void kernel_launch(void* const* d_in, const int* in_sizes, int n_in,
                              void* d_out, int out_size, void* d_ws, size_t ws_size,
                              hipStream_t stream) {
    const float* h    = (const float*)d_in[0];
    const float* dist = (const float*)d_in[1];
    const float* W1   = (const float*)d_in[2];
    const float* b1   = (const float*)d_in[3];
    const float* W2   = (const float*)d_in[4];
    const float* b2   = (const float*)d_in[5];
    const int* src    = (const int*)d_in[6];
    const int* dst    = (const int*)d_in[7];
    float* out        = (float*)d_out;

    // ws layout (ints): rec_sorted[2E] | bcnt[NBUCK] | boffs[NBUCK+1] |
    //                   bcursor[NBUCK] | offs[N+1]
    size_t needed = ((size_t)2 * N_EDGES + 3 * NBUCK + 1 + N_NODES + 1) * sizeof(int);

    if (ws_size >= needed) {
        int2* rec_sorted = (int2*)d_ws;
        int* bcnt        = (int*)d_ws + (size_t)2 * N_EDGES;
        int* boffs       = bcnt + NBUCK;           // NBUCK+1
        int* bcursor     = boffs + NBUCK + 1;
        int* offs        = bcursor + NBUCK;        // N+1

        // bucket-ordered records staged in d_out (overwritten by agg later)
        int2* brec = (int2*)d_out;

        hipMemsetAsync(bcnt, 0, NBUCK * sizeof(int), stream);
        bcount_kernel<<<PGRID, 256, 0, stream>>>(dst, bcnt);
        bscan_kernel<<<1, 1024, 0, stream>>>(bcnt, boffs, bcursor, offs);
        partition_kernel<<<PGRID, 256, 0, stream>>>(dst, src, dist, bcursor, brec);
        node_sort_kernel<<<NBUCK, 256, 0, stream>>>(brec, boffs, rec_sorted, offs);
        agg_kernel<<<(N_NODES + 3) / 4, 256, 0, stream>>>(h, offs, rec_sorted, out);
    } else {
        hipMemsetAsync(out, 0, (size_t)N_NODES * IN_FEATS * sizeof(float), stream);
        long long total = (long long)N_EDGES * 64;
        schnet_edge_kernel<<<(int)((total + 255) / 256), 256, 0, stream>>>(
            h, dist, src, dst, out);
    }

    mlp_kernel<<<2048, 256, 0, stream>>>(out, W1, b1, W2, b2);
}

// Round 10
// 216.515 us; speedup vs baseline: 4.0387x; 1.0072x over previous
//
#include <hip/hip_runtime.h>
#include <hip/hip_fp16.h>
#include <math.h>

#define IN_FEATS 64
#define N_NODES 100000
#define N_EDGES 1600000
#define BSHIFT 7
#define NPB 128                              // nodes per bucket
#define NBUCK ((N_NODES + NPB - 1) / NPB)    // 782
#define PCHUNK 8192
#define PGRID ((N_EDGES + PCHUNK - 1) / PCHUNK)  // 196

// sqrt(64 * log2(e)) : exp(-64 t^2) == exp2(-(K*t)^2)
#define KSCALE 9.6089785f

// ---------------------------------------------------------------------------
// full edge coefficient (fallback path only)
// ---------------------------------------------------------------------------
__device__ __forceinline__ float edge_coef(float d, float mu) {
    float t = d - mu;
    float rbf = __expf(-64.0f * t * t);
    float x  = (d - 0.8f) * 5.0f;
    float xc = fminf(fmaxf(x, 0.0f), 1.0f);
    float ramp = 0.5f * (__cosf(3.14159265358979323846f * xc) + 1.0f);
    float fc = (d <= 0.8f) ? 1.0f : ((d >= 1.0f) ? 0.0f : ramp);
    return rbf * fc;
}

// lane-invariant smooth cutoff (computed once per edge, in partition)
__device__ __forceinline__ float cutoff_fc(float d) {
    float x  = (d - 0.8f) * 5.0f;
    float xc = fminf(fmaxf(x, 0.0f), 1.0f);
    float ramp = 0.5f * (__cosf(3.14159265358979323846f * xc) + 1.0f);
    return (d <= 0.8f) ? 1.0f : ((d >= 1.0f) ? 0.0f : ramp);
}

__device__ __forceinline__ float rl(float v, int l) {
    return __int_as_float(__builtin_amdgcn_readlane(__float_as_int(v), l));
}

// ---------------------------------------------------------------------------
// Bucket histogram
// ---------------------------------------------------------------------------
__global__ __launch_bounds__(256) void bcount_kernel(const int* __restrict__ dst,
                                                     int* __restrict__ bcnt) {
    __shared__ int hist[NBUCK];
    int tid = threadIdx.x;
    for (int i = tid; i < NBUCK; i += 256) hist[i] = 0;
    __syncthreads();
    int e0 = blockIdx.x * PCHUNK;
    int e1 = min(e0 + PCHUNK, N_EDGES);
    for (int t = e0 + tid; t < e1; t += 256)
        atomicAdd(&hist[dst[t] >> BSHIFT], 1);
    __syncthreads();
    for (int i = tid; i < NBUCK; i += 256) {
        int hv = hist[i];
        if (hv) atomicAdd(&bcnt[i], hv);
    }
}

// ---------------------------------------------------------------------------
// Exclusive scan over buckets; inits cursor; sentinels.
// ---------------------------------------------------------------------------
__global__ __launch_bounds__(1024) void bscan_kernel(const int* __restrict__ bcnt,
                                                     int* __restrict__ boffs,
                                                     int* __restrict__ bcursor,
                                                     int* __restrict__ offs) {
    __shared__ int lds[1024];
    int tid = threadIdx.x;
    int v = (tid < NBUCK) ? bcnt[tid] : 0;
    lds[tid] = v;
    __syncthreads();
    for (int off = 1; off < 1024; off <<= 1) {
        int x = (tid >= off) ? lds[tid - off] : 0;
        __syncthreads();
        lds[tid] += x;
        __syncthreads();
    }
    if (tid < NBUCK) {
        int excl = lds[tid] - v;
        boffs[tid] = excl;
        bcursor[tid] = excl;
    }
    if (tid == 0) {
        boffs[NBUCK] = N_EDGES;
        offs[N_NODES] = N_EDGES;
    }
}

// ---------------------------------------------------------------------------
// Partition into bucket-grouped records (staged in d_out).
// Per-edge (lane-invariant) work hoisted HERE: fc(d) cosine cutoff.
// Record: {src | (dst_local<<17),  (fc_f16 << 16) | d_unorm16}
// ---------------------------------------------------------------------------
__global__ __launch_bounds__(256) void partition_kernel(const int* __restrict__ dst,
                                                        const int* __restrict__ src,
                                                        const float* __restrict__ dist,
                                                        int* __restrict__ bcursor,
                                                        int2* __restrict__ brec) {
    __shared__ int hist[NBUCK];
    __shared__ int base_[NBUCK];
    int tid = threadIdx.x;
    for (int i = tid; i < NBUCK; i += 256) hist[i] = 0;
    __syncthreads();

    int e0 = blockIdx.x * PCHUNK;
    int e1 = min(e0 + PCHUNK, N_EDGES);

    for (int t = e0 + tid; t < e1; t += 256)
        atomicAdd(&hist[dst[t] >> BSHIFT], 1);
    __syncthreads();

    for (int i = tid; i < NBUCK; i += 256) {
        int hv = hist[i];
        if (hv) base_[i] = atomicAdd(&bcursor[i], hv);
        hist[i] = 0;      // reuse as local cursor
    }
    __syncthreads();

    for (int t = e0 + tid; t < e1; t += 256) {
        int d  = dst[t];
        int b  = d >> BSHIFT;
        int r  = atomicAdd(&hist[b], 1);
        float dv = dist[t];
        float fc = cutoff_fc(dv);
        unsigned dq = (unsigned)(fminf(fmaxf(dv, 0.0f), 1.0f) * 65535.0f + 0.5f);
        unsigned hf = (unsigned)__half_as_ushort(__float2half(fc));
        int2 rec;
        rec.x = src[t] | ((d & (NPB - 1)) << 17);
        rec.y = (int)((hf << 16) | dq);
        brec[base_[b] + r] = rec;
    }
}

// ---------------------------------------------------------------------------
// Node-sort: one block per bucket -> per-node CSR (rec_sorted, offs).
// ---------------------------------------------------------------------------
__global__ __launch_bounds__(256) void node_sort_kernel(const int2* __restrict__ brec,
                                                        const int* __restrict__ boffs,
                                                        int2* __restrict__ rec_sorted,
                                                        int* __restrict__ offs) {
    __shared__ int cntL[NPB];
    __shared__ int scanL[NPB];
    __shared__ int curL[NPB];

    int b   = blockIdx.x;
    int tid = threadIdx.x;
    int beg = boffs[b];
    int end = boffs[b + 1];
    int node0 = b << BSHIFT;

    for (int i = tid; i < NPB; i += 256) cntL[i] = 0;
    __syncthreads();

    for (int t = beg + tid; t < end; t += 256)
        atomicAdd(&cntL[(brec[t].x >> 17) & (NPB - 1)], 1);
    __syncthreads();

    if (tid < NPB) scanL[tid] = cntL[tid];
    __syncthreads();
    for (int off = 1; off < NPB; off <<= 1) {
        int x = 0;
        if (tid < NPB && tid >= off) x = scanL[tid - off];
        __syncthreads();
        if (tid < NPB) scanL[tid] += x;
        __syncthreads();
    }
    if (tid < NPB) {
        int excl = scanL[tid] - cntL[tid];
        curL[tid] = excl;
        int node = node0 + tid;
        if (node < N_NODES) offs[node] = beg + excl;
    }
    __syncthreads();

    for (int t = beg + tid; t < end; t += 256) {
        int2 r = brec[t];
        int dl = (r.x >> 17) & (NPB - 1);
        int p  = atomicAdd(&curL[dl], 1);
        rec_sorted[beg + p] = r;
    }
}

// ---------------------------------------------------------------------------
// Aggregation: one wave per node, lane k owns feature k.
// Slim inner loop: unpack d (unorm16) + fc (f16), rbf via native exp2,
// fma into 2 acc chains. All cutoff math pre-hoisted to partition.
// ---------------------------------------------------------------------------
__global__ __launch_bounds__(256) void agg_kernel(
    const float* __restrict__ h,
    const int* __restrict__ offs,
    const int2* __restrict__ rec_sorted,
    float* __restrict__ out)
{
    int w    = threadIdx.x >> 6;
    int lane = threadIdx.x & 63;
    int node = blockIdx.x * 4 + w;
    if (node >= N_NODES) return;

    int beg = offs[node];
    int end = offs[node + 1];
    int m   = end - beg;
    float muK = (float)lane * (KSCALE / 63.0f);  // pre-scaled mu
    float acc0 = 0.0f, acc1 = 0.0f;

    const int2* ed = rec_sorted + beg;
    for (int i = 0; i < m; i += 8) {
        float hv[8], pc[8];
        #pragma unroll
        for (int u = 0; u < 8; ++u) {
            int idx = i + u;
            int cl  = (idx < m) ? idx : (m - 1);
            int2 r  = ed[cl];
            int s   = r.x & 0x1FFFF;
            hv[u]   = h[(size_t)s * 64 + lane];
            unsigned ry = (unsigned)r.y;
            float dK = (float)(ry & 0xFFFFu) * (KSCALE / 65535.0f);  // d pre-scaled
            float fc = __half2float(__ushort_as_half((unsigned short)(ry >> 16)));
            float t  = dK - muK;
            float e  = __expf(-0.69314718056f * t * t);   // exp2(-t^2) via v_exp
            pc[u] = (idx < m) ? fc * e : 0.0f;
        }
        #pragma unroll
        for (int u = 0; u < 8; u += 2) {
            acc0 = fmaf(hv[u],     pc[u],     acc0);
            acc1 = fmaf(hv[u + 1], pc[u + 1], acc1);
        }
    }
    out[(size_t)node * 64 + lane] = acc0 + acc1;
}

// ---------------------------------------------------------------------------
// MLP in place on d_out (register-resident W, readlane broadcast, zero LDS).
// ---------------------------------------------------------------------------
__global__ __launch_bounds__(256) void mlp_kernel(
    float* __restrict__ io,
    const float* __restrict__ W1, const float* __restrict__ b1,
    const float* __restrict__ W2, const float* __restrict__ b2)
{
    int tid  = threadIdx.x;
    int lane = tid & 63;
    int w    = tid >> 6;

    float w1r[64], w2r[64];
    #pragma unroll
    for (int k = 0; k < 64; ++k) {
        w1r[k] = W1[k * 64 + lane];
        w2r[k] = W2[k * 64 + lane];
    }
    float bb1 = b1[lane];
    float bb2 = b2[lane];

    int wid = blockIdx.x * 4 + w;
    int nw  = gridDim.x * 4;

    for (int n = wid * 2; n < N_NODES; n += nw * 2) {
        float rA = io[(size_t)n * 64 + lane];
        float rB = io[(size_t)(n + 1) * 64 + lane];

        float a0 = bb1, a1 = 0.f, a2 = 0.f, a3 = 0.f;
        float c0 = bb1, c1 = 0.f, c2 = 0.f, c3 = 0.f;
        #pragma unroll
        for (int k = 0; k < 64; k += 4) {
            a0 = fmaf(rl(rA, k + 0), w1r[k + 0], a0);
            a1 = fmaf(rl(rA, k + 1), w1r[k + 1], a1);
            a2 = fmaf(rl(rA, k + 2), w1r[k + 2], a2);
            a3 = fmaf(rl(rA, k + 3), w1r[k + 3], a3);
            c0 = fmaf(rl(rB, k + 0), w1r[k + 0], c0);
            c1 = fmaf(rl(rB, k + 1), w1r[k + 1], c1);
            c2 = fmaf(rl(rB, k + 2), w1r[k + 2], c2);
            c3 = fmaf(rl(rB, k + 3), w1r[k + 3], c3);
        }
        float hA = (a0 + a1) + (a2 + a3);
        float hB = (c0 + c1) + (c2 + c3);
        hA = (hA > 20.0f) ? hA : log1pf(__expf(hA));
        hB = (hB > 20.0f) ? hB : log1pf(__expf(hB));

        float o0 = bb2, o1 = 0.f, o2 = 0.f, o3 = 0.f;
        float p0 = bb2, p1 = 0.f, p2 = 0.f, p3 = 0.f;
        #pragma unroll
        for (int k = 0; k < 64; k += 4) {
            o0 = fmaf(rl(hA, k + 0), w2r[k + 0], o0);
            o1 = fmaf(rl(hA, k + 1), w2r[k + 1], o1);
            o2 = fmaf(rl(hA, k + 2), w2r[k + 2], o2);
            o3 = fmaf(rl(hA, k + 3), w2r[k + 3], o3);
            p0 = fmaf(rl(hB, k + 0), w2r[k + 0], p0);
            p1 = fmaf(rl(hB, k + 1), w2r[k + 1], p1);
            p2 = fmaf(rl(hB, k + 2), w2r[k + 2], p2);
            p3 = fmaf(rl(hB, k + 3), w2r[k + 3], p3);
        }
        io[(size_t)n * 64 + lane]       = (o0 + o1) + (o2 + o3);
        io[(size_t)(n + 1) * 64 + lane] = (p0 + p1) + (p2 + p3);
    }
}

// ---------------------------------------------------------------------------
// Fallback (ws too small): atomic scatter-add path.
// ---------------------------------------------------------------------------
__global__ __launch_bounds__(256) void schnet_edge_kernel(
    const float* __restrict__ h,
    const float* __restrict__ dist,
    const int* __restrict__ src_idx,
    const int* __restrict__ dst_idx,
    float* __restrict__ agg)
{
    long long idx = (long long)blockIdx.x * 256 + threadIdx.x;
    int e = (int)(idx >> 6);
    if (e >= N_EDGES) return;
    int k = (int)(idx & 63);
    float d = dist[e];
    float c = edge_coef(d, (float)k * (1.0f / 63.0f));
    int s  = src_idx[e];
    int dn = dst_idx[e];
    atomicAdd(&agg[(long long)dn * 64 + k], h[(long long)s * 64 + k] * c);
}

extern "C" void kernel_launch(void* const* d_in, const int* in_sizes, int n_in,
                              void* d_out, int out_size, void* d_ws, size_t ws_size,
                              hipStream_t stream) {
    const float* h    = (const float*)d_in[0];
    const float* dist = (const float*)d_in[1];
    const float* W1   = (const float*)d_in[2];
    const float* b1   = (const float*)d_in[3];
    const float* W2   = (const float*)d_in[4];
    const float* b2   = (const float*)d_in[5];
    const int* src    = (const int*)d_in[6];
    const int* dst    = (const int*)d_in[7];
    float* out        = (float*)d_out;

    // ws layout (ints): rec_sorted[2E] | bcnt[NBUCK] | boffs[NBUCK+1] |
    //                   bcursor[NBUCK] | offs[N+1]
    size_t needed = ((size_t)2 * N_EDGES + 3 * NBUCK + 1 + N_NODES + 1) * sizeof(int);

    if (ws_size >= needed) {
        int2* rec_sorted = (int2*)d_ws;
        int* bcnt        = (int*)d_ws + (size_t)2 * N_EDGES;
        int* boffs       = bcnt + NBUCK;           // NBUCK+1
        int* bcursor     = boffs + NBUCK + 1;
        int* offs        = bcursor + NBUCK;        // N+1

        // bucket-ordered records staged in d_out (overwritten by agg later)
        int2* brec = (int2*)d_out;

        hipMemsetAsync(bcnt, 0, NBUCK * sizeof(int), stream);
        bcount_kernel<<<PGRID, 256, 0, stream>>>(dst, bcnt);
        bscan_kernel<<<1, 1024, 0, stream>>>(bcnt, boffs, bcursor, offs);
        partition_kernel<<<PGRID, 256, 0, stream>>>(dst, src, dist, bcursor, brec);
        node_sort_kernel<<<NBUCK, 256, 0, stream>>>(brec, boffs, rec_sorted, offs);
        agg_kernel<<<(N_NODES + 3) / 4, 256, 0, stream>>>(h, offs, rec_sorted, out);
    } else {
        hipMemsetAsync(out, 0, (size_t)N_NODES * IN_FEATS * sizeof(float), stream);
        long long total = (long long)N_EDGES * 64;
        schnet_edge_kernel<<<(int)((total + 255) / 256), 256, 0, stream>>>(
            h, dist, src, dst, out);
    }

    mlp_kernel<<<2048, 256, 0, stream>>>(out, W1, b1, W2, b2);
}

// Round 11
// 190.546 us; speedup vs baseline: 4.5892x; 1.1363x over previous
//
#include <hip/hip_runtime.h>
#include <hip/hip_fp16.h>
#include <math.h>

#define IN_FEATS 64
#define N_NODES 100000
#define N_EDGES 1600000
#define BSHIFT 7
#define NPB 128                              // nodes per bucket
#define NBUCK ((N_NODES + NPB - 1) / NPB)    // 782
#define CAP 4088                             // padded bucket capacity (mean 2046, sigma 45)
#define PCHUNK 8192
#define PGRID ((N_EDGES + PCHUNK - 1) / PCHUNK)  // 196

// sqrt(64 * log2(e)) : exp(-64 t^2) == exp2(-((K t))^2)
#define KSCALE 9.6089785f

// ---------------------------------------------------------------------------
// full edge coefficient (fallback path only)
// ---------------------------------------------------------------------------
__device__ __forceinline__ float edge_coef(float d, float mu) {
    float t = d - mu;
    float rbf = __expf(-64.0f * t * t);
    float x  = (d - 0.8f) * 5.0f;
    float xc = fminf(fmaxf(x, 0.0f), 1.0f);
    float ramp = 0.5f * (__cosf(3.14159265358979323846f * xc) + 1.0f);
    float fc = (d <= 0.8f) ? 1.0f : ((d >= 1.0f) ? 0.0f : ramp);
    return rbf * fc;
}

// lane-invariant smooth cutoff (computed once per edge, in partition)
__device__ __forceinline__ float cutoff_fc(float d) {
    float x  = (d - 0.8f) * 5.0f;
    float xc = fminf(fmaxf(x, 0.0f), 1.0f);
    float ramp = 0.5f * (__cosf(3.14159265358979323846f * xc) + 1.0f);
    return (d <= 0.8f) ? 1.0f : ((d >= 1.0f) ? 0.0f : ramp);
}

__device__ __forceinline__ float rl(float v, int l) {
    return __int_as_float(__builtin_amdgcn_readlane(__float_as_int(v), l));
}

// ---------------------------------------------------------------------------
// Init: bcursor[b] = b*CAP (reservation cursors into padded staging)
// ---------------------------------------------------------------------------
__global__ __launch_bounds__(256) void init_kernel(int* __restrict__ bcursor,
                                                   int* __restrict__ offs) {
    int i = blockIdx.x * 256 + threadIdx.x;
    if (i < NBUCK) bcursor[i] = i * CAP;
    if (i == 0) offs[N_NODES] = N_EDGES;   // sentinel
}

// ---------------------------------------------------------------------------
// Partition into padded bucket staging (d_out). Block-chunked reservation:
// per-block LDS histogram, one contiguous run per (block,bucket) -> no
// global write amplification. fc(d) hoisted here (lane-invariant work).
// Record: {src | (dst_local<<17),  (fc_f16 << 16) | d_unorm16}
// ---------------------------------------------------------------------------
__global__ __launch_bounds__(256) void partition_kernel(const int* __restrict__ dst,
                                                        const int* __restrict__ src,
                                                        const float* __restrict__ dist,
                                                        int* __restrict__ bcursor,
                                                        int2* __restrict__ brec) {
    __shared__ int hist[NBUCK];
    __shared__ int base_[NBUCK];
    int tid = threadIdx.x;
    for (int i = tid; i < NBUCK; i += 256) hist[i] = 0;
    __syncthreads();

    int e0 = blockIdx.x * PCHUNK;
    int e1 = min(e0 + PCHUNK, N_EDGES);

    for (int t = e0 + tid; t < e1; t += 256)
        atomicAdd(&hist[dst[t] >> BSHIFT], 1);
    __syncthreads();

    for (int i = tid; i < NBUCK; i += 256) {
        int hv = hist[i];
        if (hv) base_[i] = atomicAdd(&bcursor[i], hv);
        hist[i] = 0;      // reuse as local cursor
    }
    __syncthreads();

    for (int t = e0 + tid; t < e1; t += 256) {
        int d  = dst[t];
        int b  = d >> BSHIFT;
        int r  = atomicAdd(&hist[b], 1);
        float dv = dist[t];
        float fc = cutoff_fc(dv);
        unsigned dq = (unsigned)(fminf(fmaxf(dv, 0.0f), 1.0f) * 65535.0f + 0.5f);
        unsigned hf = (unsigned)__half_as_ushort(__float2half(fc));
        int2 rec;
        rec.x = src[t] | ((d & (NPB - 1)) << 17);
        rec.y = (int)((hf << 16) | dq);
        brec[(size_t)base_[b] + r] = rec;
    }
}

// ---------------------------------------------------------------------------
// Compact scan (post-partition): cnt[b] = bcursor[b]-b*CAP; boffs = excl scan.
// ---------------------------------------------------------------------------
__global__ __launch_bounds__(1024) void bscan_kernel(const int* __restrict__ bcursor,
                                                     int* __restrict__ boffs) {
    __shared__ int lds[1024];
    int tid = threadIdx.x;
    int v = (tid < NBUCK) ? (bcursor[tid] - tid * CAP) : 0;
    lds[tid] = v;
    __syncthreads();
    for (int off = 1; off < 1024; off <<= 1) {
        int x = (tid >= off) ? lds[tid - off] : 0;
        __syncthreads();
        lds[tid] += x;
        __syncthreads();
    }
    if (tid < NBUCK) boffs[tid] = lds[tid] - v;   // exclusive
    if (tid == 0) boffs[NBUCK] = N_EDGES;
}

// ---------------------------------------------------------------------------
// Node-sort: one block per bucket. Reads padded brec[b*CAP ..], writes
// compact per-node-sorted rec_sorted at boffs[b], emits per-node CSR offs.
// ---------------------------------------------------------------------------
__global__ __launch_bounds__(256) void node_sort_kernel(const int2* __restrict__ brec,
                                                        const int* __restrict__ boffs,
                                                        int2* __restrict__ rec_sorted,
                                                        int* __restrict__ offs) {
    __shared__ int cntL[NPB];
    __shared__ int scanL[NPB];
    __shared__ int curL[NPB];

    int b   = blockIdx.x;
    int tid = threadIdx.x;
    int beg = boffs[b];
    int cnt = boffs[b + 1] - beg;
    size_t pbase = (size_t)b * CAP;
    int node0 = b << BSHIFT;

    for (int i = tid; i < NPB; i += 256) cntL[i] = 0;
    __syncthreads();

    for (int t = tid; t < cnt; t += 256)
        atomicAdd(&cntL[(brec[pbase + t].x >> 17) & (NPB - 1)], 1);
    __syncthreads();

    if (tid < NPB) scanL[tid] = cntL[tid];
    __syncthreads();
    for (int off = 1; off < NPB; off <<= 1) {
        int x = 0;
        if (tid < NPB && tid >= off) x = scanL[tid - off];
        __syncthreads();
        if (tid < NPB) scanL[tid] += x;
        __syncthreads();
    }
    if (tid < NPB) {
        int excl = scanL[tid] - cntL[tid];
        curL[tid] = excl;
        int node = node0 + tid;
        if (node < N_NODES) offs[node] = beg + excl;
    }
    __syncthreads();

    for (int t = tid; t < cnt; t += 256) {
        int2 r = brec[pbase + t];
        int dl = (r.x >> 17) & (NPB - 1);
        int p  = atomicAdd(&curL[dl], 1);
        rec_sorted[(size_t)beg + p] = r;
    }
}

// ---------------------------------------------------------------------------
// Aggregation: one wave per node, lane k owns feature k.
// Wave-uniform record path: readfirstlane record fields -> SALU unpack,
// SGPR-base gather addressing (zero per-record VALU addr), exp2 with neg
// modifier. Uniform main loop (x8) + scalar tail: no per-record selects.
// ---------------------------------------------------------------------------
__global__ __launch_bounds__(256) void agg_kernel(
    const float* __restrict__ h,
    const int* __restrict__ offs,
    const int2* __restrict__ rec_sorted,
    float* __restrict__ out)
{
    int w    = threadIdx.x >> 6;
    int lane = threadIdx.x & 63;
    int node = blockIdx.x * 4 + w;
    if (node >= N_NODES) return;

    int beg = __builtin_amdgcn_readfirstlane(offs[node]);
    int end = __builtin_amdgcn_readfirstlane(offs[node + 1]);
    float muK = (float)lane * (KSCALE / 63.0f);
    float acc0 = 0.0f, acc1 = 0.0f;

#define REC(J, ACC) { \
        int2 r_ = rec_sorted[(size_t)(J)]; \
        int rx_ = __builtin_amdgcn_readfirstlane(r_.x); \
        unsigned ry_ = (unsigned)__builtin_amdgcn_readfirstlane(r_.y); \
        float hv_ = h[((size_t)(rx_ & 0x1FFFF) << 6) + lane]; \
        float dK_ = (float)(ry_ & 0xFFFFu) * (KSCALE / 65535.0f); \
        float fc_ = __half2float(__ushort_as_half((unsigned short)(ry_ >> 16))); \
        float t_  = dK_ - muK; \
        float e_  = exp2f(-(t_ * t_)); \
        ACC = fmaf(hv_, fc_ * e_, ACC); }

    int i = beg;
    int main_end = beg + ((end - beg) & ~7);
    for (; i < main_end; i += 8) {
        REC(i + 0, acc0) REC(i + 1, acc1) REC(i + 2, acc0) REC(i + 3, acc1)
        REC(i + 4, acc0) REC(i + 5, acc1) REC(i + 6, acc0) REC(i + 7, acc1)
    }
    for (; i < end; ++i) { REC(i, acc0) }
#undef REC

    out[(size_t)node * 64 + lane] = acc0 + acc1;
}

// ---------------------------------------------------------------------------
// MLP in place on d_out (register-resident W, readlane broadcast, zero LDS).
// ---------------------------------------------------------------------------
__global__ __launch_bounds__(256) void mlp_kernel(
    float* __restrict__ io,
    const float* __restrict__ W1, const float* __restrict__ b1,
    const float* __restrict__ W2, const float* __restrict__ b2)
{
    int tid  = threadIdx.x;
    int lane = tid & 63;
    int w    = tid >> 6;

    float w1r[64], w2r[64];
    #pragma unroll
    for (int k = 0; k < 64; ++k) {
        w1r[k] = W1[k * 64 + lane];
        w2r[k] = W2[k * 64 + lane];
    }
    float bb1 = b1[lane];
    float bb2 = b2[lane];

    int wid = blockIdx.x * 4 + w;
    int nw  = gridDim.x * 4;

    for (int n = wid * 2; n < N_NODES; n += nw * 2) {
        float rA = io[(size_t)n * 64 + lane];
        float rB = io[(size_t)(n + 1) * 64 + lane];

        float a0 = bb1, a1 = 0.f, a2 = 0.f, a3 = 0.f;
        float c0 = bb1, c1 = 0.f, c2 = 0.f, c3 = 0.f;
        #pragma unroll
        for (int k = 0; k < 64; k += 4) {
            a0 = fmaf(rl(rA, k + 0), w1r[k + 0], a0);
            a1 = fmaf(rl(rA, k + 1), w1r[k + 1], a1);
            a2 = fmaf(rl(rA, k + 2), w1r[k + 2], a2);
            a3 = fmaf(rl(rA, k + 3), w1r[k + 3], a3);
            c0 = fmaf(rl(rB, k + 0), w1r[k + 0], c0);
            c1 = fmaf(rl(rB, k + 1), w1r[k + 1], c1);
            c2 = fmaf(rl(rB, k + 2), w1r[k + 2], c2);
            c3 = fmaf(rl(rB, k + 3), w1r[k + 3], c3);
        }
        float hA = (a0 + a1) + (a2 + a3);
        float hB = (c0 + c1) + (c2 + c3);
        hA = (hA > 20.0f) ? hA : log1pf(__expf(hA));
        hB = (hB > 20.0f) ? hB : log1pf(__expf(hB));

        float o0 = bb2, o1 = 0.f, o2 = 0.f, o3 = 0.f;
        float p0 = bb2, p1 = 0.f, p2 = 0.f, p3 = 0.f;
        #pragma unroll
        for (int k = 0; k < 64; k += 4) {
            o0 = fmaf(rl(hA, k + 0), w2r[k + 0], o0);
            o1 = fmaf(rl(hA, k + 1), w2r[k + 1], o1);
            o2 = fmaf(rl(hA, k + 2), w2r[k + 2], o2);
            o3 = fmaf(rl(hA, k + 3), w2r[k + 3], o3);
            p0 = fmaf(rl(hB, k + 0), w2r[k + 0], p0);
            p1 = fmaf(rl(hB, k + 1), w2r[k + 1], p1);
            p2 = fmaf(rl(hB, k + 2), w2r[k + 2], p2);
            p3 = fmaf(rl(hB, k + 3), w2r[k + 3], p3);
        }
        io[(size_t)n * 64 + lane]       = (o0 + o1) + (o2 + o3);
        io[(size_t)(n + 1) * 64 + lane] = (p0 + p1) + (p2 + p3);
    }
}

// ---------------------------------------------------------------------------
// Fallback (ws too small): atomic scatter-add path.
// ---------------------------------------------------------------------------
__global__ __launch_bounds__(256) void schnet_edge_kernel(
    const float* __restrict__ h,
    const float* __restrict__ dist,
    const int* __restrict__ src_idx,
    const int* __restrict__ dst_idx,
    float* __restrict__ agg)
{
    long long idx = (long long)blockIdx.x * 256 + threadIdx.x;
    int e = (int)(idx >> 6);
    if (e >= N_EDGES) return;
    int k = (int)(idx & 63);
    float d = dist[e];
    float c = edge_coef(d, (float)k * (1.0f / 63.0f));
    int s  = src_idx[e];
    int dn = dst_idx[e];
    atomicAdd(&agg[(long long)dn * 64 + k], h[(long long)s * 64 + k] * c);
}

extern "C" void kernel_launch(void* const* d_in, const int* in_sizes, int n_in,
                              void* d_out, int out_size, void* d_ws, size_t ws_size,
                              hipStream_t stream) {
    const float* h    = (const float*)d_in[0];
    const float* dist = (const float*)d_in[1];
    const float* W1   = (const float*)d_in[2];
    const float* b1   = (const float*)d_in[3];
    const float* W2   = (const float*)d_in[4];
    const float* b2   = (const float*)d_in[5];
    const int* src    = (const int*)d_in[6];
    const int* dst    = (const int*)d_in[7];
    float* out        = (float*)d_out;

    // ws layout (ints): rec_sorted[2E] | boffs[NBUCK+1] | bcursor[NBUCK] | offs[N+1]
    size_t needed = ((size_t)2 * N_EDGES + NBUCK + 1 + NBUCK + N_NODES + 1) * sizeof(int);

    if (ws_size >= needed) {
        int2* rec_sorted = (int2*)d_ws;
        int* boffs       = (int*)d_ws + (size_t)2 * N_EDGES;   // NBUCK+1
        int* bcursor     = boffs + NBUCK + 1;
        int* offs        = bcursor + NBUCK;                    // N+1

        // padded bucket staging in d_out (782*4088 recs = 25.57MB <= 25.6MB)
        int2* brec = (int2*)d_out;

        init_kernel<<<(NBUCK + 255) / 256, 256, 0, stream>>>(bcursor, offs);
        partition_kernel<<<PGRID, 256, 0, stream>>>(dst, src, dist, bcursor, brec);
        bscan_kernel<<<1, 1024, 0, stream>>>(bcursor, boffs);
        node_sort_kernel<<<NBUCK, 256, 0, stream>>>(brec, boffs, rec_sorted, offs);
        agg_kernel<<<N_NODES / 4, 256, 0, stream>>>(h, offs, rec_sorted, out);
    } else {
        hipMemsetAsync(out, 0, (size_t)N_NODES * IN_FEATS * sizeof(float), stream);
        long long total = (long long)N_EDGES * 64;
        schnet_edge_kernel<<<(int)((total + 255) / 256), 256, 0, stream>>>(
            h, dist, src, dst, out);
    }

    mlp_kernel<<<2048, 256, 0, stream>>>(out, W1, b1, W2, b2);
}

// Round 12
// 176.452 us; speedup vs baseline: 4.9557x; 1.0799x over previous
//
#include <hip/hip_runtime.h>
#include <hip/hip_fp16.h>
#include <math.h>

#define IN_FEATS 64
#define N_NODES 100000
#define N_EDGES 1600000
#define BSHIFT 7
#define NPB 128                              // nodes per bucket
#define NBUCK ((N_NODES + NPB - 1) / NPB)    // 782
#define CAP 4088                             // padded bucket capacity (mean 2046, sigma 45)
#define PCHUNK 8192
#define PGRID ((N_EDGES + PCHUNK - 1) / PCHUNK)  // 196

// sqrt(64 * log2(e)) : exp(-64 t^2) == exp2(-((K t))^2)
#define KSCALE 9.6089785f

// ---------------------------------------------------------------------------
// full edge coefficient (fallback path only)
// ---------------------------------------------------------------------------
__device__ __forceinline__ float edge_coef(float d, float mu) {
    float t = d - mu;
    float rbf = __expf(-64.0f * t * t);
    float x  = (d - 0.8f) * 5.0f;
    float xc = fminf(fmaxf(x, 0.0f), 1.0f);
    float ramp = 0.5f * (__cosf(3.14159265358979323846f * xc) + 1.0f);
    float fc = (d <= 0.8f) ? 1.0f : ((d >= 1.0f) ? 0.0f : ramp);
    return rbf * fc;
}

// lane-invariant smooth cutoff (computed once per edge, in partition)
__device__ __forceinline__ float cutoff_fc(float d) {
    float x  = (d - 0.8f) * 5.0f;
    float xc = fminf(fmaxf(x, 0.0f), 1.0f);
    float ramp = 0.5f * (__cosf(3.14159265358979323846f * xc) + 1.0f);
    return (d <= 0.8f) ? 1.0f : ((d >= 1.0f) ? 0.0f : ramp);
}

// ---------------------------------------------------------------------------
// Init: bcursor[b] = b*CAP, offs sentinel, W2 transpose into ws.
// ---------------------------------------------------------------------------
__global__ __launch_bounds__(256) void init_kernel(int* __restrict__ bcursor,
                                                   int* __restrict__ offs,
                                                   const float* __restrict__ W2,
                                                   float* __restrict__ W2T) {
    int i = blockIdx.x * 256 + threadIdx.x;
    if (i < NBUCK) bcursor[i] = i * CAP;
    if (i == 0) offs[N_NODES] = N_EDGES;   // sentinel
    if (i < 64 * 64) W2T[(i & 63) * 64 + (i >> 6)] = W2[i];
}

// ---------------------------------------------------------------------------
// Partition into padded bucket staging (d_out). Block-chunked reservation.
// Record: {src | (dst_local<<17),  (fc_f16 << 16) | d_unorm16}
// ---------------------------------------------------------------------------
__global__ __launch_bounds__(256) void partition_kernel(const int* __restrict__ dst,
                                                        const int* __restrict__ src,
                                                        const float* __restrict__ dist,
                                                        int* __restrict__ bcursor,
                                                        int2* __restrict__ brec) {
    __shared__ int hist[NBUCK];
    __shared__ int base_[NBUCK];
    int tid = threadIdx.x;
    for (int i = tid; i < NBUCK; i += 256) hist[i] = 0;
    __syncthreads();

    int e0 = blockIdx.x * PCHUNK;
    int e1 = min(e0 + PCHUNK, N_EDGES);

    for (int t = e0 + tid; t < e1; t += 256)
        atomicAdd(&hist[dst[t] >> BSHIFT], 1);
    __syncthreads();

    for (int i = tid; i < NBUCK; i += 256) {
        int hv = hist[i];
        if (hv) base_[i] = atomicAdd(&bcursor[i], hv);
        hist[i] = 0;      // reuse as local cursor
    }
    __syncthreads();

    for (int t = e0 + tid; t < e1; t += 256) {
        int d  = dst[t];
        int b  = d >> BSHIFT;
        int r  = atomicAdd(&hist[b], 1);
        float dv = dist[t];
        float fc = cutoff_fc(dv);
        unsigned dq = (unsigned)(fminf(fmaxf(dv, 0.0f), 1.0f) * 65535.0f + 0.5f);
        unsigned hf = (unsigned)__half_as_ushort(__float2half(fc));
        int2 rec;
        rec.x = src[t] | ((d & (NPB - 1)) << 17);
        rec.y = (int)((hf << 16) | dq);
        brec[(size_t)base_[b] + r] = rec;
    }
}

// ---------------------------------------------------------------------------
// Compact scan (post-partition): cnt[b] = bcursor[b]-b*CAP; boffs = excl scan.
// ---------------------------------------------------------------------------
__global__ __launch_bounds__(1024) void bscan_kernel(const int* __restrict__ bcursor,
                                                     int* __restrict__ boffs) {
    __shared__ int lds[1024];
    int tid = threadIdx.x;
    int v = (tid < NBUCK) ? (bcursor[tid] - tid * CAP) : 0;
    lds[tid] = v;
    __syncthreads();
    for (int off = 1; off < 1024; off <<= 1) {
        int x = (tid >= off) ? lds[tid - off] : 0;
        __syncthreads();
        lds[tid] += x;
        __syncthreads();
    }
    if (tid < NBUCK) boffs[tid] = lds[tid] - v;   // exclusive
    if (tid == 0) boffs[NBUCK] = N_EDGES;
}

// ---------------------------------------------------------------------------
// Node-sort: one block per bucket -> compact per-node CSR (rec_sorted, offs).
// ---------------------------------------------------------------------------
__global__ __launch_bounds__(256) void node_sort_kernel(const int2* __restrict__ brec,
                                                        const int* __restrict__ boffs,
                                                        int2* __restrict__ rec_sorted,
                                                        int* __restrict__ offs) {
    __shared__ int cntL[NPB];
    __shared__ int scanL[NPB];
    __shared__ int curL[NPB];

    int b   = blockIdx.x;
    int tid = threadIdx.x;
    int beg = boffs[b];
    int cnt = boffs[b + 1] - beg;
    size_t pbase = (size_t)b * CAP;
    int node0 = b << BSHIFT;

    for (int i = tid; i < NPB; i += 256) cntL[i] = 0;
    __syncthreads();

    for (int t = tid; t < cnt; t += 256)
        atomicAdd(&cntL[(brec[pbase + t].x >> 17) & (NPB - 1)], 1);
    __syncthreads();

    if (tid < NPB) scanL[tid] = cntL[tid];
    __syncthreads();
    for (int off = 1; off < NPB; off <<= 1) {
        int x = 0;
        if (tid < NPB && tid >= off) x = scanL[tid - off];
        __syncthreads();
        if (tid < NPB) scanL[tid] += x;
        __syncthreads();
    }
    if (tid < NPB) {
        int excl = scanL[tid] - cntL[tid];
        curL[tid] = excl;
        int node = node0 + tid;
        if (node < N_NODES) offs[node] = beg + excl;
    }
    __syncthreads();

    for (int t = tid; t < cnt; t += 256) {
        int2 r = brec[pbase + t];
        int dl = (r.x >> 17) & (NPB - 1);
        int p  = atomicAdd(&curL[dl], 1);
        rec_sorted[(size_t)beg + p] = r;
    }
}

// ---------------------------------------------------------------------------
// Aggregation: one wave per node, lane k owns feature k.
// Wave-uniform record path (SALU unpack, SGPR-base gather), exp2 neg-mod.
// ---------------------------------------------------------------------------
__global__ __launch_bounds__(256) void agg_kernel(
    const float* __restrict__ h,
    const int* __restrict__ offs,
    const int2* __restrict__ rec_sorted,
    float* __restrict__ out)
{
    int w    = threadIdx.x >> 6;
    int lane = threadIdx.x & 63;
    int node = blockIdx.x * 4 + w;
    if (node >= N_NODES) return;

    int beg = __builtin_amdgcn_readfirstlane(offs[node]);
    int end = __builtin_amdgcn_readfirstlane(offs[node + 1]);
    float muK = (float)lane * (KSCALE / 63.0f);
    float acc0 = 0.0f, acc1 = 0.0f;

#define REC(J, ACC) { \
        int2 r_ = rec_sorted[(size_t)(J)]; \
        int rx_ = __builtin_amdgcn_readfirstlane(r_.x); \
        unsigned ry_ = (unsigned)__builtin_amdgcn_readfirstlane(r_.y); \
        float hv_ = h[((size_t)(rx_ & 0x1FFFF) << 6) + lane]; \
        float dK_ = (float)(ry_ & 0xFFFFu) * (KSCALE / 65535.0f); \
        float fc_ = __half2float(__ushort_as_half((unsigned short)(ry_ >> 16))); \
        float t_  = dK_ - muK; \
        float e_  = exp2f(-(t_ * t_)); \
        ACC = fmaf(hv_, fc_ * e_, ACC); }

    int i = beg;
    int main_end = beg + ((end - beg) & ~7);
    for (; i < main_end; i += 8) {
        REC(i + 0, acc0) REC(i + 1, acc1) REC(i + 2, acc0) REC(i + 3, acc1)
        REC(i + 4, acc0) REC(i + 5, acc1) REC(i + 6, acc0) REC(i + 7, acc1)
    }
    for (; i < end; ++i) { REC(i, acc0) }
#undef REC

    out[(size_t)node * 64 + lane] = acc0 + acc1;
}

// ---------------------------------------------------------------------------
// MLP, lane = node. W is wave-uniform -> SMEM s_load; one v_fmac per MAC.
// Layer1: dynamic k-outer (row via VMEM float4), static j-inner (acc[64]).
// Layer2: dynamic j-outer (W2T rows), static k-inner (acc = hid, in regs).
// No LDS, no readlane, no dynamic reg-array indexing.
// ---------------------------------------------------------------------------
__global__ __launch_bounds__(256) void mlp_kernel(
    float* __restrict__ io,
    const float* __restrict__ W1, const float* __restrict__ b1,
    const float* __restrict__ W2T, const float* __restrict__ b2)
{
    int lane = threadIdx.x & 63;
    int wv   = threadIdx.x >> 6;
    int node = (blockIdx.x * 4 + wv) * 64 + lane;
    bool valid = node < N_NODES;
    int nclamp = valid ? node : (N_NODES - 1);

    const float4* rowp = (const float4*)(io + (size_t)nclamp * 64);

    float acc[64];
    #pragma unroll
    for (int j = 0; j < 64; ++j) acc[j] = b1[j];

    for (int kc = 0; kc < 16; ++kc) {
        float4 rv = rowp[kc];
        const float* wr = W1 + kc * 256;
        #pragma unroll
        for (int j = 0; j < 64; ++j) acc[j] = fmaf(rv.x, wr[j], acc[j]);
        #pragma unroll
        for (int j = 0; j < 64; ++j) acc[j] = fmaf(rv.y, wr[64 + j], acc[j]);
        #pragma unroll
        for (int j = 0; j < 64; ++j) acc[j] = fmaf(rv.z, wr[128 + j], acc[j]);
        #pragma unroll
        for (int j = 0; j < 64; ++j) acc[j] = fmaf(rv.w, wr[192 + j], acc[j]);
    }

    // softplus: log(1+e^x) = log2(1+2^(x*log2e)) * ln2
    #pragma unroll
    for (int j = 0; j < 64; ++j) {
        float v = acc[j];
        float e = exp2f(v * 1.44269504089f);
        float sp = 0.69314718056f * __log2f(1.0f + e);
        acc[j] = (v > 20.0f) ? v : sp;
    }

    float* orow = io + (size_t)node * 64;
    for (int jc = 0; jc < 16; ++jc) {
        float o[4];
        #pragma unroll
        for (int ju = 0; ju < 4; ++ju) {
            int j = jc * 4 + ju;
            const float* wr = W2T + j * 64;
            float s0 = 0.f, s1 = 0.f, s2 = 0.f, s3 = 0.f;
            #pragma unroll
            for (int k = 0; k < 64; k += 4) {
                s0 = fmaf(acc[k],     wr[k],     s0);
                s1 = fmaf(acc[k + 1], wr[k + 1], s1);
                s2 = fmaf(acc[k + 2], wr[k + 2], s2);
                s3 = fmaf(acc[k + 3], wr[k + 3], s3);
            }
            o[ju] = b2[j] + ((s0 + s1) + (s2 + s3));
        }
        if (valid)
            *(float4*)(orow + jc * 4) = make_float4(o[0], o[1], o[2], o[3]);
    }
}

// ---------------------------------------------------------------------------
// Fallback (ws too small): atomic scatter-add path + simple MLP.
// ---------------------------------------------------------------------------
__global__ __launch_bounds__(256) void schnet_edge_kernel(
    const float* __restrict__ h,
    const float* __restrict__ dist,
    const int* __restrict__ src_idx,
    const int* __restrict__ dst_idx,
    float* __restrict__ agg)
{
    long long idx = (long long)blockIdx.x * 256 + threadIdx.x;
    int e = (int)(idx >> 6);
    if (e >= N_EDGES) return;
    int k = (int)(idx & 63);
    float d = dist[e];
    float c = edge_coef(d, (float)k * (1.0f / 63.0f));
    int s  = src_idx[e];
    int dn = dst_idx[e];
    atomicAdd(&agg[(long long)dn * 64 + k], h[(long long)s * 64 + k] * c);
}

__global__ __launch_bounds__(256) void mlp_fallback_kernel(
    float* __restrict__ io,
    const float* __restrict__ W1, const float* __restrict__ b1,
    const float* __restrict__ W2, const float* __restrict__ b2)
{
    __shared__ float sW1[64 * 64];
    __shared__ float sW2[64 * 64];
    __shared__ float sRow[4][64];
    __shared__ float sHid[4][64];
    int tid = threadIdx.x;
    for (int i = tid; i < 4096; i += 256) { sW1[i] = W1[i]; sW2[i] = W2[i]; }
    __syncthreads();
    int lane = tid & 63, w = tid >> 6;
    float bb1 = b1[lane], bb2 = b2[lane];
    for (int base = blockIdx.x * 4; base < N_NODES; base += gridDim.x * 4) {
        int node = base + w;
        if (node < N_NODES) sRow[w][lane] = io[(size_t)node * 64 + lane];
        __syncthreads();
        float a = bb1;
        #pragma unroll
        for (int k = 0; k < 64; ++k) a = fmaf(sRow[w][k], sW1[k * 64 + lane], a);
        sHid[w][lane] = (a > 20.f) ? a : log1pf(__expf(a));
        __syncthreads();
        float c = bb2;
        #pragma unroll
        for (int k = 0; k < 64; ++k) c = fmaf(sHid[w][k], sW2[k * 64 + lane], c);
        if (node < N_NODES) io[(size_t)node * 64 + lane] = c;
        __syncthreads();
    }
}

extern "C" void kernel_launch(void* const* d_in, const int* in_sizes, int n_in,
                              void* d_out, int out_size, void* d_ws, size_t ws_size,
                              hipStream_t stream) {
    const float* h    = (const float*)d_in[0];
    const float* dist = (const float*)d_in[1];
    const float* W1   = (const float*)d_in[2];
    const float* b1   = (const float*)d_in[3];
    const float* W2   = (const float*)d_in[4];
    const float* b2   = (const float*)d_in[5];
    const int* src    = (const int*)d_in[6];
    const int* dst    = (const int*)d_in[7];
    float* out        = (float*)d_out;

    // ws layout (ints): rec_sorted[2E] | boffs[NBUCK+1] | bcursor[NBUCK] |
    //                   offs[N+1] | W2T[4096 floats]
    size_t needed = ((size_t)2 * N_EDGES + NBUCK + 1 + NBUCK + N_NODES + 1 + 4096)
                    * sizeof(int);

    if (ws_size >= needed) {
        int2* rec_sorted = (int2*)d_ws;
        int* boffs       = (int*)d_ws + (size_t)2 * N_EDGES;   // NBUCK+1
        int* bcursor     = boffs + NBUCK + 1;
        int* offs        = bcursor + NBUCK;                    // N+1
        float* W2T       = (float*)(offs + N_NODES + 1);       // 4096

        // padded bucket staging in d_out (782*4088 recs = 25.57MB <= 25.6MB)
        int2* brec = (int2*)d_out;

        init_kernel<<<16, 256, 0, stream>>>(bcursor, offs, W2, W2T);
        partition_kernel<<<PGRID, 256, 0, stream>>>(dst, src, dist, bcursor, brec);
        bscan_kernel<<<1, 1024, 0, stream>>>(bcursor, boffs);
        node_sort_kernel<<<NBUCK, 256, 0, stream>>>(brec, boffs, rec_sorted, offs);
        agg_kernel<<<N_NODES / 4, 256, 0, stream>>>(h, offs, rec_sorted, out);
        mlp_kernel<<<(N_NODES + 255) / 256, 256, 0, stream>>>(out, W1, b1, W2T, b2);
    } else {
        hipMemsetAsync(out, 0, (size_t)N_NODES * IN_FEATS * sizeof(float), stream);
        long long total = (long long)N_EDGES * 64;
        schnet_edge_kernel<<<(int)((total + 255) / 256), 256, 0, stream>>>(
            h, dist, src, dst, out);
        mlp_fallback_kernel<<<2048, 256, 0, stream>>>(out, W1, b1, W2, b2);
    }
}

// Round 13
// 165.986 us; speedup vs baseline: 5.2682x; 1.0631x over previous
//
#include <hip/hip_runtime.h>
#include <hip/hip_fp16.h>
#include <math.h>

#define IN_FEATS 64
#define N_NODES 100000
#define N_EDGES 1600000
#define BSHIFT 7
#define NPB 128                              // nodes per bucket
#define NBUCK ((N_NODES + NPB - 1) / NPB)    // 782
#define CAP 4088                             // padded bucket capacity (mean 2046, sigma 45)
#define PCHUNK 8192
#define PGRID ((N_EDGES + PCHUNK - 1) / PCHUNK)  // 196

// sqrt(64 * log2(e)) : exp(-64 t^2) == exp2(-((K t))^2)
#define KSCALE 9.6089785f

// ---------------------------------------------------------------------------
// full edge coefficient (fallback path only)
// ---------------------------------------------------------------------------
__device__ __forceinline__ float edge_coef(float d, float mu) {
    float t = d - mu;
    float rbf = __expf(-64.0f * t * t);
    float x  = (d - 0.8f) * 5.0f;
    float xc = fminf(fmaxf(x, 0.0f), 1.0f);
    float ramp = 0.5f * (__cosf(3.14159265358979323846f * xc) + 1.0f);
    float fc = (d <= 0.8f) ? 1.0f : ((d >= 1.0f) ? 0.0f : ramp);
    return rbf * fc;
}

// lane-invariant smooth cutoff (computed once per edge, in partition)
__device__ __forceinline__ float cutoff_fc(float d) {
    float x  = (d - 0.8f) * 5.0f;
    float xc = fminf(fmaxf(x, 0.0f), 1.0f);
    float ramp = 0.5f * (__cosf(3.14159265358979323846f * xc) + 1.0f);
    return (d <= 0.8f) ? 1.0f : ((d >= 1.0f) ? 0.0f : ramp);
}

// ---------------------------------------------------------------------------
// Init: bcursor[b] = b*CAP, offs sentinel, W2 transpose into ws.
// ---------------------------------------------------------------------------
__global__ __launch_bounds__(256) void init_kernel(int* __restrict__ bcursor,
                                                   int* __restrict__ offs,
                                                   const float* __restrict__ W2,
                                                   float* __restrict__ W2T) {
    int i = blockIdx.x * 256 + threadIdx.x;
    if (i < NBUCK) bcursor[i] = i * CAP;
    if (i == 0) offs[N_NODES] = N_EDGES;   // sentinel
    if (i < 64 * 64) W2T[(i & 63) * 64 + (i >> 6)] = W2[i];
}

// ---------------------------------------------------------------------------
// Partition into padded bucket staging (d_out). Block-chunked reservation.
// 1024 threads/block: 196 blocks x 16 waves = 3.1 waves/SIMD (was 0.77).
// Record: {src | (dst_local<<17),  (log2fc_f16 << 16) | d_unorm16}
// ---------------------------------------------------------------------------
__global__ __launch_bounds__(1024) void partition_kernel(const int* __restrict__ dst,
                                                         const int* __restrict__ src,
                                                         const float* __restrict__ dist,
                                                         int* __restrict__ bcursor,
                                                         int2* __restrict__ brec) {
    __shared__ int hist[NBUCK];
    __shared__ int base_[NBUCK];
    int tid = threadIdx.x;
    for (int i = tid; i < NBUCK; i += 1024) hist[i] = 0;
    __syncthreads();

    int e0 = blockIdx.x * PCHUNK;
    int e1 = min(e0 + PCHUNK, N_EDGES);

    for (int t = e0 + tid; t < e1; t += 1024)
        atomicAdd(&hist[dst[t] >> BSHIFT], 1);
    __syncthreads();

    for (int i = tid; i < NBUCK; i += 1024) {
        int hv = hist[i];
        if (hv) base_[i] = atomicAdd(&bcursor[i], hv);
        hist[i] = 0;      // reuse as local cursor
    }
    __syncthreads();

    for (int t = e0 + tid; t < e1; t += 1024) {
        int d  = dst[t];
        int b  = d >> BSHIFT;
        int r  = atomicAdd(&hist[b], 1);
        float dv = dist[t];
        float fc = cutoff_fc(dv);
        // log2(fc); fc==0 -> -512 (exp2(-512-t^2)==0)
        float lfc = (fc > 0.0f) ? __log2f(fc) : -512.0f;
        unsigned dq = (unsigned)(fminf(fmaxf(dv, 0.0f), 1.0f) * 65535.0f + 0.5f);
        unsigned hf = (unsigned)__half_as_ushort(__float2half(lfc));
        int2 rec;
        rec.x = src[t] | ((d & (NPB - 1)) << 17);
        rec.y = (int)((hf << 16) | dq);
        brec[(size_t)base_[b] + r] = rec;
    }
}

// ---------------------------------------------------------------------------
// Compact scan (post-partition): cnt[b] = bcursor[b]-b*CAP; boffs = excl scan.
// ---------------------------------------------------------------------------
__global__ __launch_bounds__(1024) void bscan_kernel(const int* __restrict__ bcursor,
                                                     int* __restrict__ boffs) {
    __shared__ int lds[1024];
    int tid = threadIdx.x;
    int v = (tid < NBUCK) ? (bcursor[tid] - tid * CAP) : 0;
    lds[tid] = v;
    __syncthreads();
    for (int off = 1; off < 1024; off <<= 1) {
        int x = (tid >= off) ? lds[tid - off] : 0;
        __syncthreads();
        lds[tid] += x;
        __syncthreads();
    }
    if (tid < NBUCK) boffs[tid] = lds[tid] - v;   // exclusive
    if (tid == 0) boffs[NBUCK] = N_EDGES;
}

// ---------------------------------------------------------------------------
// Node-sort: one block per bucket -> compact per-node CSR (rec_sorted, offs).
// ---------------------------------------------------------------------------
__global__ __launch_bounds__(256) void node_sort_kernel(const int2* __restrict__ brec,
                                                        const int* __restrict__ boffs,
                                                        int2* __restrict__ rec_sorted,
                                                        int* __restrict__ offs) {
    __shared__ int cntL[NPB];
    __shared__ int scanL[NPB];
    __shared__ int curL[NPB];

    int b   = blockIdx.x;
    int tid = threadIdx.x;
    int beg = boffs[b];
    int cnt = boffs[b + 1] - beg;
    size_t pbase = (size_t)b * CAP;
    int node0 = b << BSHIFT;

    for (int i = tid; i < NPB; i += 256) cntL[i] = 0;
    __syncthreads();

    for (int t = tid; t < cnt; t += 256)
        atomicAdd(&cntL[(brec[pbase + t].x >> 17) & (NPB - 1)], 1);
    __syncthreads();

    if (tid < NPB) scanL[tid] = cntL[tid];
    __syncthreads();
    for (int off = 1; off < NPB; off <<= 1) {
        int x = 0;
        if (tid < NPB && tid >= off) x = scanL[tid - off];
        __syncthreads();
        if (tid < NPB) scanL[tid] += x;
        __syncthreads();
    }
    if (tid < NPB) {
        int excl = scanL[tid] - cntL[tid];
        curL[tid] = excl;
        int node = node0 + tid;
        if (node < N_NODES) offs[node] = beg + excl;
    }
    __syncthreads();

    for (int t = tid; t < cnt; t += 256) {
        int2 r = brec[pbase + t];
        int dl = (r.x >> 17) & (NPB - 1);
        int p  = atomicAdd(&curL[dl], 1);
        rec_sorted[(size_t)beg + p] = r;
    }
}

// ---------------------------------------------------------------------------
// Aggregation: one wave per node, lane k owns feature k.
// Scalar record path (uniform addr -> s_load), coef = exp2(lfc - t^2):
// 5 VALU + 1 trans per record.
// ---------------------------------------------------------------------------
__global__ __launch_bounds__(256) void agg_kernel(
    const float* __restrict__ h,
    const int* __restrict__ offs,
    const int2* __restrict__ rec_sorted,
    float* __restrict__ out)
{
    int w    = threadIdx.x >> 6;
    int lane = threadIdx.x & 63;
    int node = blockIdx.x * 4 + w;
    if (node >= N_NODES) return;

    int beg = __builtin_amdgcn_readfirstlane(offs[node]);
    int end = __builtin_amdgcn_readfirstlane(offs[node + 1]);
    float muK = (float)lane * (KSCALE / 63.0f);
    float acc0 = 0.0f, acc1 = 0.0f;

#define REC(J, ACC) { \
        int2 r_ = rec_sorted[(size_t)(J)]; \
        int rx_ = __builtin_amdgcn_readfirstlane(r_.x); \
        unsigned ry_ = (unsigned)__builtin_amdgcn_readfirstlane(r_.y); \
        float hv_ = h[((size_t)(rx_ & 0x1FFFF) << 6) + lane]; \
        float dqf_ = (float)(ry_ & 0xFFFFu); \
        float lfc_ = __half2float(__ushort_as_half((unsigned short)(ry_ >> 16))); \
        float t_  = fmaf(dqf_, (KSCALE / 65535.0f), -muK); \
        float a_  = fmaf(-t_, t_, lfc_); \
        ACC = fmaf(hv_, exp2f(a_), ACC); }

    int i = beg;
    int main_end = beg + ((end - beg) & ~7);
    for (; i < main_end; i += 8) {
        REC(i + 0, acc0) REC(i + 1, acc1) REC(i + 2, acc0) REC(i + 3, acc1)
        REC(i + 4, acc0) REC(i + 5, acc1) REC(i + 6, acc0) REC(i + 7, acc1)
    }
    for (; i < end; ++i) { REC(i, acc0) }
#undef REC

    out[(size_t)node * 64 + lane] = acc0 + acc1;
}

// ---------------------------------------------------------------------------
// MLP, lane = node. W wave-uniform -> scalar loads; one v_fmac per MAC.
// Output computed in 64B-line chunks (o[16]), 4 float4 stores back-to-back
// -> full-line write combining (fixes 3x write amplification).
// ---------------------------------------------------------------------------
__global__ __launch_bounds__(256) void mlp_kernel(
    float* __restrict__ io,
    const float* __restrict__ W1, const float* __restrict__ b1,
    const float* __restrict__ W2T, const float* __restrict__ b2)
{
    int lane = threadIdx.x & 63;
    int wv   = threadIdx.x >> 6;
    int node = (blockIdx.x * 4 + wv) * 64 + lane;
    bool valid = node < N_NODES;
    int nclamp = valid ? node : (N_NODES - 1);

    const float4* rowp = (const float4*)(io + (size_t)nclamp * 64);

    float acc[64];
    #pragma unroll
    for (int j = 0; j < 64; ++j) acc[j] = b1[j];

    for (int kc = 0; kc < 16; ++kc) {
        float4 rv = rowp[kc];
        const float* wr = W1 + kc * 256;
        #pragma unroll
        for (int j = 0; j < 64; ++j) acc[j] = fmaf(rv.x, wr[j], acc[j]);
        #pragma unroll
        for (int j = 0; j < 64; ++j) acc[j] = fmaf(rv.y, wr[64 + j], acc[j]);
        #pragma unroll
        for (int j = 0; j < 64; ++j) acc[j] = fmaf(rv.z, wr[128 + j], acc[j]);
        #pragma unroll
        for (int j = 0; j < 64; ++j) acc[j] = fmaf(rv.w, wr[192 + j], acc[j]);
    }

    // softplus: log(1+e^x) = log2(1+2^(x*log2e)) * ln2
    #pragma unroll
    for (int j = 0; j < 64; ++j) {
        float v = acc[j];
        float e = exp2f(v * 1.44269504089f);
        float sp = 0.69314718056f * __log2f(1.0f + e);
        acc[j] = (v > 20.0f) ? v : sp;
    }

    float* orow = io + (size_t)node * 64;
    #pragma unroll
    for (int lc = 0; lc < 4; ++lc) {
        float o[16];
        #pragma unroll
        for (int ju = 0; ju < 16; ++ju) {
            int j = lc * 16 + ju;
            const float* wr = W2T + j * 64;
            float s0 = 0.f, s1 = 0.f, s2 = 0.f, s3 = 0.f;
            #pragma unroll
            for (int k = 0; k < 64; k += 4) {
                s0 = fmaf(acc[k],     wr[k],     s0);
                s1 = fmaf(acc[k + 1], wr[k + 1], s1);
                s2 = fmaf(acc[k + 2], wr[k + 2], s2);
                s3 = fmaf(acc[k + 3], wr[k + 3], s3);
            }
            o[ju] = b2[j] + ((s0 + s1) + (s2 + s3));
        }
        if (valid) {
            float4* op = (float4*)(orow + lc * 16);
            op[0] = make_float4(o[0],  o[1],  o[2],  o[3]);
            op[1] = make_float4(o[4],  o[5],  o[6],  o[7]);
            op[2] = make_float4(o[8],  o[9],  o[10], o[11]);
            op[3] = make_float4(o[12], o[13], o[14], o[15]);
        }
    }
}

// ---------------------------------------------------------------------------
// Fallback (ws too small): atomic scatter-add path + simple MLP.
// ---------------------------------------------------------------------------
__global__ __launch_bounds__(256) void schnet_edge_kernel(
    const float* __restrict__ h,
    const float* __restrict__ dist,
    const int* __restrict__ src_idx,
    const int* __restrict__ dst_idx,
    float* __restrict__ agg)
{
    long long idx = (long long)blockIdx.x * 256 + threadIdx.x;
    int e = (int)(idx >> 6);
    if (e >= N_EDGES) return;
    int k = (int)(idx & 63);
    float d = dist[e];
    float c = edge_coef(d, (float)k * (1.0f / 63.0f));
    int s  = src_idx[e];
    int dn = dst_idx[e];
    atomicAdd(&agg[(long long)dn * 64 + k], h[(long long)s * 64 + k] * c);
}

__global__ __launch_bounds__(256) void mlp_fallback_kernel(
    float* __restrict__ io,
    const float* __restrict__ W1, const float* __restrict__ b1,
    const float* __restrict__ W2, const float* __restrict__ b2)
{
    __shared__ float sW1[64 * 64];
    __shared__ float sW2[64 * 64];
    __shared__ float sRow[4][64];
    __shared__ float sHid[4][64];
    int tid = threadIdx.x;
    for (int i = tid; i < 4096; i += 256) { sW1[i] = W1[i]; sW2[i] = W2[i]; }
    __syncthreads();
    int lane = tid & 63, w = tid >> 6;
    float bb1 = b1[lane], bb2 = b2[lane];
    for (int base = blockIdx.x * 4; base < N_NODES; base += gridDim.x * 4) {
        int node = base + w;
        if (node < N_NODES) sRow[w][lane] = io[(size_t)node * 64 + lane];
        __syncthreads();
        float a = bb1;
        #pragma unroll
        for (int k = 0; k < 64; ++k) a = fmaf(sRow[w][k], sW1[k * 64 + lane], a);
        sHid[w][lane] = (a > 20.f) ? a : log1pf(__expf(a));
        __syncthreads();
        float c = bb2;
        #pragma unroll
        for (int k = 0; k < 64; ++k) c = fmaf(sHid[w][k], sW2[k * 64 + lane], c);
        if (node < N_NODES) io[(size_t)node * 64 + lane] = c;
        __syncthreads();
    }
}

extern "C" void kernel_launch(void* const* d_in, const int* in_sizes, int n_in,
                              void* d_out, int out_size, void* d_ws, size_t ws_size,
                              hipStream_t stream) {
    const float* h    = (const float*)d_in[0];
    const float* dist = (const float*)d_in[1];
    const float* W1   = (const float*)d_in[2];
    const float* b1   = (const float*)d_in[3];
    const float* W2   = (const float*)d_in[4];
    const float* b2   = (const float*)d_in[5];
    const int* src    = (const int*)d_in[6];
    const int* dst    = (const int*)d_in[7];
    float* out        = (float*)d_out;

    // ws layout (ints): rec_sorted[2E] | boffs[NBUCK+1] | bcursor[NBUCK] |
    //                   offs[N+1] | W2T[4096 floats]
    size_t needed = ((size_t)2 * N_EDGES + NBUCK + 1 + NBUCK + N_NODES + 1 + 4096)
                    * sizeof(int);

    if (ws_size >= needed) {
        int2* rec_sorted = (int2*)d_ws;
        int* boffs       = (int*)d_ws + (size_t)2 * N_EDGES;   // NBUCK+1
        int* bcursor     = boffs + NBUCK + 1;
        int* offs        = bcursor + NBUCK;                    // N+1
        float* W2T       = (float*)(offs + N_NODES + 1);       // 4096

        // padded bucket staging in d_out (782*4088 recs = 25.57MB <= 25.6MB)
        int2* brec = (int2*)d_out;

        init_kernel<<<16, 256, 0, stream>>>(bcursor, offs, W2, W2T);
        partition_kernel<<<PGRID, 1024, 0, stream>>>(dst, src, dist, bcursor, brec);
        bscan_kernel<<<1, 1024, 0, stream>>>(bcursor, boffs);
        node_sort_kernel<<<NBUCK, 256, 0, stream>>>(brec, boffs, rec_sorted, offs);
        agg_kernel<<<N_NODES / 4, 256, 0, stream>>>(h, offs, rec_sorted, out);
        mlp_kernel<<<(N_NODES + 255) / 256, 256, 0, stream>>>(out, W1, b1, W2T, b2);
    } else {
        hipMemsetAsync(out, 0, (size_t)N_NODES * IN_FEATS * sizeof(float), stream);
        long long total = (long long)N_EDGES * 64;
        schnet_edge_kernel<<<(int)((total + 255) / 256), 256, 0, stream>>>(
            h, dist, src, dst, out);
        mlp_fallback_kernel<<<2048, 256, 0, stream>>>(out, W1, b1, W2, b2);
    }
}

// Round 14
// 163.243 us; speedup vs baseline: 5.3567x; 1.0168x over previous
//
#include <hip/hip_runtime.h>
#include <hip/hip_fp16.h>
#include <math.h>

#define IN_FEATS 64
#define N_NODES 100000
#define N_EDGES 1600000
#define BSHIFT 7
#define NPB 128                              // nodes per bucket
#define NBUCK ((N_NODES + NPB - 1) / NPB)    // 782
#define CAP 4088                             // padded bucket capacity (mean 2046, sigma 45)
#define PCHUNK 8192
#define PGRID ((N_EDGES + PCHUNK - 1) / PCHUNK)  // 196

// sqrt(64 * log2(e)) : exp(-64 t^2) == exp2(-((K t))^2)
#define KSCALE 9.6089785f

// ---------------------------------------------------------------------------
// full edge coefficient (fallback path only)
// ---------------------------------------------------------------------------
__device__ __forceinline__ float edge_coef(float d, float mu) {
    float t = d - mu;
    float rbf = __expf(-64.0f * t * t);
    float x  = (d - 0.8f) * 5.0f;
    float xc = fminf(fmaxf(x, 0.0f), 1.0f);
    float ramp = 0.5f * (__cosf(3.14159265358979323846f * xc) + 1.0f);
    float fc = (d <= 0.8f) ? 1.0f : ((d >= 1.0f) ? 0.0f : ramp);
    return rbf * fc;
}

// lane-invariant smooth cutoff (computed once per edge, in partition)
__device__ __forceinline__ float cutoff_fc(float d) {
    float x  = (d - 0.8f) * 5.0f;
    float xc = fminf(fmaxf(x, 0.0f), 1.0f);
    float ramp = 0.5f * (__cosf(3.14159265358979323846f * xc) + 1.0f);
    return (d <= 0.8f) ? 1.0f : ((d >= 1.0f) ? 0.0f : ramp);
}

// ---------------------------------------------------------------------------
// Init: bcursor[b] = b*CAP, offs sentinel, W2 transpose into ws.
// ---------------------------------------------------------------------------
__global__ __launch_bounds__(256) void init_kernel(int* __restrict__ bcursor,
                                                   int* __restrict__ offs,
                                                   const float* __restrict__ W2,
                                                   float* __restrict__ W2T) {
    int i = blockIdx.x * 256 + threadIdx.x;
    if (i < NBUCK) bcursor[i] = i * CAP;
    if (i == 0) offs[N_NODES] = N_EDGES;   // sentinel
    if (i < 64 * 64) W2T[(i & 63) * 64 + (i >> 6)] = W2[i];
}

// ---------------------------------------------------------------------------
// Partition into padded bucket staging (d_out). Block-chunked reservation.
// 1024 threads/block.
// Record: {src | (dst_local<<17),  (log2fc_f16 << 16) | d_unorm16}
// ---------------------------------------------------------------------------
__global__ __launch_bounds__(1024) void partition_kernel(const int* __restrict__ dst,
                                                         const int* __restrict__ src,
                                                         const float* __restrict__ dist,
                                                         int* __restrict__ bcursor,
                                                         int2* __restrict__ brec) {
    __shared__ int hist[NBUCK];
    __shared__ int base_[NBUCK];
    int tid = threadIdx.x;
    for (int i = tid; i < NBUCK; i += 1024) hist[i] = 0;
    __syncthreads();

    int e0 = blockIdx.x * PCHUNK;
    int e1 = min(e0 + PCHUNK, N_EDGES);

    for (int t = e0 + tid; t < e1; t += 1024)
        atomicAdd(&hist[dst[t] >> BSHIFT], 1);
    __syncthreads();

    for (int i = tid; i < NBUCK; i += 1024) {
        int hv = hist[i];
        if (hv) base_[i] = atomicAdd(&bcursor[i], hv);
        hist[i] = 0;      // reuse as local cursor
    }
    __syncthreads();

    for (int t = e0 + tid; t < e1; t += 1024) {
        int d  = dst[t];
        int b  = d >> BSHIFT;
        int r  = atomicAdd(&hist[b], 1);
        float dv = dist[t];
        float fc = cutoff_fc(dv);
        // log2(fc); fc==0 -> -512 (exp2(-512-t^2)==0)
        float lfc = (fc > 0.0f) ? __log2f(fc) : -512.0f;
        unsigned dq = (unsigned)(fminf(fmaxf(dv, 0.0f), 1.0f) * 65535.0f + 0.5f);
        unsigned hf = (unsigned)__half_as_ushort(__float2half(lfc));
        int2 rec;
        rec.x = src[t] | ((d & (NPB - 1)) << 17);
        rec.y = (int)((hf << 16) | dq);
        brec[(size_t)base_[b] + r] = rec;
    }
}

// ---------------------------------------------------------------------------
// Compact scan (post-partition): cnt[b] = bcursor[b]-b*CAP; boffs = excl scan.
// ---------------------------------------------------------------------------
__global__ __launch_bounds__(1024) void bscan_kernel(const int* __restrict__ bcursor,
                                                     int* __restrict__ boffs) {
    __shared__ int lds[1024];
    int tid = threadIdx.x;
    int v = (tid < NBUCK) ? (bcursor[tid] - tid * CAP) : 0;
    lds[tid] = v;
    __syncthreads();
    for (int off = 1; off < 1024; off <<= 1) {
        int x = (tid >= off) ? lds[tid - off] : 0;
        __syncthreads();
        lds[tid] += x;
        __syncthreads();
    }
    if (tid < NBUCK) boffs[tid] = lds[tid] - v;   // exclusive
    if (tid == 0) boffs[NBUCK] = N_EDGES;
}

// ---------------------------------------------------------------------------
// Node-sort: one block per bucket -> compact per-node CSR (rec_sorted, offs).
// ---------------------------------------------------------------------------
__global__ __launch_bounds__(256) void node_sort_kernel(const int2* __restrict__ brec,
                                                        const int* __restrict__ boffs,
                                                        int2* __restrict__ rec_sorted,
                                                        int* __restrict__ offs) {
    __shared__ int cntL[NPB];
    __shared__ int scanL[NPB];
    __shared__ int curL[NPB];

    int b   = blockIdx.x;
    int tid = threadIdx.x;
    int beg = boffs[b];
    int cnt = boffs[b + 1] - beg;
    size_t pbase = (size_t)b * CAP;
    int node0 = b << BSHIFT;

    for (int i = tid; i < NPB; i += 256) cntL[i] = 0;
    __syncthreads();

    for (int t = tid; t < cnt; t += 256)
        atomicAdd(&cntL[(brec[pbase + t].x >> 17) & (NPB - 1)], 1);
    __syncthreads();

    if (tid < NPB) scanL[tid] = cntL[tid];
    __syncthreads();
    for (int off = 1; off < NPB; off <<= 1) {
        int x = 0;
        if (tid < NPB && tid >= off) x = scanL[tid - off];
        __syncthreads();
        if (tid < NPB) scanL[tid] += x;
        __syncthreads();
    }
    if (tid < NPB) {
        int excl = scanL[tid] - cntL[tid];
        curL[tid] = excl;
        int node = node0 + tid;
        if (node < N_NODES) offs[node] = beg + excl;
    }
    __syncthreads();

    for (int t = tid; t < cnt; t += 256) {
        int2 r = brec[pbase + t];
        int dl = (r.x >> 17) & (NPB - 1);
        int p  = atomicAdd(&curL[dl], 1);
        rec_sorted[(size_t)beg + p] = r;
    }
}

// ---------------------------------------------------------------------------
// Aggregation: one wave per node, lane k owns feature k.
// Scalar record path (uniform addr -> s_load), coef = exp2(lfc - t^2).
// ---------------------------------------------------------------------------
__global__ __launch_bounds__(256) void agg_kernel(
    const float* __restrict__ h,
    const int* __restrict__ offs,
    const int2* __restrict__ rec_sorted,
    float* __restrict__ out)
{
    int w    = threadIdx.x >> 6;
    int lane = threadIdx.x & 63;
    int node = blockIdx.x * 4 + w;
    if (node >= N_NODES) return;

    int beg = __builtin_amdgcn_readfirstlane(offs[node]);
    int end = __builtin_amdgcn_readfirstlane(offs[node + 1]);
    float muK = (float)lane * (KSCALE / 63.0f);
    float acc0 = 0.0f, acc1 = 0.0f;

#define REC(J, ACC) { \
        int2 r_ = rec_sorted[(size_t)(J)]; \
        int rx_ = __builtin_amdgcn_readfirstlane(r_.x); \
        unsigned ry_ = (unsigned)__builtin_amdgcn_readfirstlane(r_.y); \
        float hv_ = h[((size_t)(rx_ & 0x1FFFF) << 6) + lane]; \
        float dqf_ = (float)(ry_ & 0xFFFFu); \
        float lfc_ = __half2float(__ushort_as_half((unsigned short)(ry_ >> 16))); \
        float t_  = fmaf(dqf_, (KSCALE / 65535.0f), -muK); \
        float a_  = fmaf(-t_, t_, lfc_); \
        ACC = fmaf(hv_, exp2f(a_), ACC); }

    int i = beg;
    int main_end = beg + ((end - beg) & ~7);
    for (; i < main_end; i += 8) {
        REC(i + 0, acc0) REC(i + 1, acc1) REC(i + 2, acc0) REC(i + 3, acc1)
        REC(i + 4, acc0) REC(i + 5, acc1) REC(i + 6, acc0) REC(i + 7, acc1)
    }
    for (; i < end; ++i) { REC(i, acc0) }
#undef REC

    out[(size_t)node * 64 + lane] = acc0 + acc1;
}

// ---------------------------------------------------------------------------
// MLP, lane = node. W wave-uniform -> scalar loads; one v_fmac per MAC.
// v3: FULL ROW PRELOADED (16 float4 in flight -> one vmcnt drain), then
// layer1 + softplus + layer2 are uninterrupted VALU with 64 indep chains.
// __launch_bounds__(256,1): allow high VGPR (grid-capped occupancy anyway).
// ---------------------------------------------------------------------------
__global__ __launch_bounds__(256, 1) void mlp_kernel(
    float* __restrict__ io,
    const float* __restrict__ W1, const float* __restrict__ b1,
    const float* __restrict__ W2T, const float* __restrict__ b2)
{
    int lane = threadIdx.x & 63;
    int wv   = threadIdx.x >> 6;
    int node = (blockIdx.x * 4 + wv) * 64 + lane;
    bool valid = node < N_NODES;
    int nclamp = valid ? node : (N_NODES - 1);

    const float4* rowp = (const float4*)(io + (size_t)nclamp * 64);

    // issue all 16 row loads back-to-back (256B/lane in flight)
    float4 rv[16];
    #pragma unroll
    for (int kc = 0; kc < 16; ++kc) rv[kc] = rowp[kc];

    float acc[64];
    #pragma unroll
    for (int j = 0; j < 64; ++j) acc[j] = b1[j];

    #pragma unroll
    for (int kc = 0; kc < 16; ++kc) {
        const float* wr = W1 + kc * 256;
        #pragma unroll
        for (int j = 0; j < 64; ++j) acc[j] = fmaf(rv[kc].x, wr[j], acc[j]);
        #pragma unroll
        for (int j = 0; j < 64; ++j) acc[j] = fmaf(rv[kc].y, wr[64 + j], acc[j]);
        #pragma unroll
        for (int j = 0; j < 64; ++j) acc[j] = fmaf(rv[kc].z, wr[128 + j], acc[j]);
        #pragma unroll
        for (int j = 0; j < 64; ++j) acc[j] = fmaf(rv[kc].w, wr[192 + j], acc[j]);
    }

    // softplus: log(1+e^x) = log2(1+2^(x*log2e)) * ln2
    #pragma unroll
    for (int j = 0; j < 64; ++j) {
        float v = acc[j];
        float e = exp2f(v * 1.44269504089f);
        float sp = 0.69314718056f * __log2f(1.0f + e);
        acc[j] = (v > 20.0f) ? v : sp;
    }

    float* orow = io + (size_t)node * 64;
    #pragma unroll
    for (int lc = 0; lc < 4; ++lc) {
        float o[16];
        #pragma unroll
        for (int ju = 0; ju < 16; ++ju) {
            int j = lc * 16 + ju;
            const float* wr = W2T + j * 64;
            float s0 = 0.f, s1 = 0.f, s2 = 0.f, s3 = 0.f;
            #pragma unroll
            for (int k = 0; k < 64; k += 4) {
                s0 = fmaf(acc[k],     wr[k],     s0);
                s1 = fmaf(acc[k + 1], wr[k + 1], s1);
                s2 = fmaf(acc[k + 2], wr[k + 2], s2);
                s3 = fmaf(acc[k + 3], wr[k + 3], s3);
            }
            o[ju] = b2[j] + ((s0 + s1) + (s2 + s3));
        }
        if (valid) {
            float4* op = (float4*)(orow + lc * 16);
            op[0] = make_float4(o[0],  o[1],  o[2],  o[3]);
            op[1] = make_float4(o[4],  o[5],  o[6],  o[7]);
            op[2] = make_float4(o[8],  o[9],  o[10], o[11]);
            op[3] = make_float4(o[12], o[13], o[14], o[15]);
        }
    }
}

// ---------------------------------------------------------------------------
// Fallback (ws too small): atomic scatter-add path + simple MLP.
// ---------------------------------------------------------------------------
__global__ __launch_bounds__(256) void schnet_edge_kernel(
    const float* __restrict__ h,
    const float* __restrict__ dist,
    const int* __restrict__ src_idx,
    const int* __restrict__ dst_idx,
    float* __restrict__ agg)
{
    long long idx = (long long)blockIdx.x * 256 + threadIdx.x;
    int e = (int)(idx >> 6);
    if (e >= N_EDGES) return;
    int k = (int)(idx & 63);
    float d = dist[e];
    float c = edge_coef(d, (float)k * (1.0f / 63.0f));
    int s  = src_idx[e];
    int dn = dst_idx[e];
    atomicAdd(&agg[(long long)dn * 64 + k], h[(long long)s * 64 + k] * c);
}

__global__ __launch_bounds__(256) void mlp_fallback_kernel(
    float* __restrict__ io,
    const float* __restrict__ W1, const float* __restrict__ b1,
    const float* __restrict__ W2, const float* __restrict__ b2)
{
    __shared__ float sW1[64 * 64];
    __shared__ float sW2[64 * 64];
    __shared__ float sRow[4][64];
    __shared__ float sHid[4][64];
    int tid = threadIdx.x;
    for (int i = tid; i < 4096; i += 256) { sW1[i] = W1[i]; sW2[i] = W2[i]; }
    __syncthreads();
    int lane = tid & 63, w = tid >> 6;
    float bb1 = b1[lane], bb2 = b2[lane];
    for (int base = blockIdx.x * 4; base < N_NODES; base += gridDim.x * 4) {
        int node = base + w;
        if (node < N_NODES) sRow[w][lane] = io[(size_t)node * 64 + lane];
        __syncthreads();
        float a = bb1;
        #pragma unroll
        for (int k = 0; k < 64; ++k) a = fmaf(sRow[w][k], sW1[k * 64 + lane], a);
        sHid[w][lane] = (a > 20.f) ? a : log1pf(__expf(a));
        __syncthreads();
        float c = bb2;
        #pragma unroll
        for (int k = 0; k < 64; ++k) c = fmaf(sHid[w][k], sW2[k * 64 + lane], c);
        if (node < N_NODES) io[(size_t)node * 64 + lane] = c;
        __syncthreads();
    }
}

extern "C" void kernel_launch(void* const* d_in, const int* in_sizes, int n_in,
                              void* d_out, int out_size, void* d_ws, size_t ws_size,
                              hipStream_t stream) {
    const float* h    = (const float*)d_in[0];
    const float* dist = (const float*)d_in[1];
    const float* W1   = (const float*)d_in[2];
    const float* b1   = (const float*)d_in[3];
    const float* W2   = (const float*)d_in[4];
    const float* b2   = (const float*)d_in[5];
    const int* src    = (const int*)d_in[6];
    const int* dst    = (const int*)d_in[7];
    float* out        = (float*)d_out;

    // ws layout (ints): rec_sorted[2E] | boffs[NBUCK+1] | bcursor[NBUCK] |
    //                   offs[N+1] | W2T[4096 floats]
    size_t needed = ((size_t)2 * N_EDGES + NBUCK + 1 + NBUCK + N_NODES + 1 + 4096)
                    * sizeof(int);

    if (ws_size >= needed) {
        int2* rec_sorted = (int2*)d_ws;
        int* boffs       = (int*)d_ws + (size_t)2 * N_EDGES;   // NBUCK+1
        int* bcursor     = boffs + NBUCK + 1;
        int* offs        = bcursor + NBUCK;                    // N+1
        float* W2T       = (float*)(offs + N_NODES + 1);       // 4096

        // padded bucket staging in d_out (782*4088 recs = 25.57MB <= 25.6MB)
        int2* brec = (int2*)d_out;

        init_kernel<<<16, 256, 0, stream>>>(bcursor, offs, W2, W2T);
        partition_kernel<<<PGRID, 1024, 0, stream>>>(dst, src, dist, bcursor, brec);
        bscan_kernel<<<1, 1024, 0, stream>>>(bcursor, boffs);
        node_sort_kernel<<<NBUCK, 256, 0, stream>>>(brec, boffs, rec_sorted, offs);
        agg_kernel<<<N_NODES / 4, 256, 0, stream>>>(h, offs, rec_sorted, out);
        mlp_kernel<<<(N_NODES + 255) / 256, 256, 0, stream>>>(out, W1, b1, W2T, b2);
    } else {
        hipMemsetAsync(out, 0, (size_t)N_NODES * IN_FEATS * sizeof(float), stream);
        long long total = (long long)N_EDGES * 64;
        schnet_edge_kernel<<<(int)((total + 255) / 256), 256, 0, stream>>>(
            h, dist, src, dst, out);
        mlp_fallback_kernel<<<2048, 256, 0, stream>>>(out, W1, b1, W2, b2);
    }
}